// Round 3
// baseline (3115.168 us; speedup 1.0000x reference)
//
#include <hip/hip_runtime.h>
#include <math.h>

#define Bz 64
#define Tz 12000
#define Pz 50
#define Dz 200
#define Lz 12
#define Hz 10
#define HDz 20
#define FFz 800
#define Nz 240
#define Sz 241
#define NRDz 482
#define NCz 1000
#define BS (Bz * Sz)          // 15424
#define SCALEq 0.22360679774997896f

typedef __attribute__((ext_vector_type(8))) short bf16x8;
typedef __attribute__((ext_vector_type(4))) float f32x4;

static __device__ __forceinline__ short f2b(float f) {
    unsigned u = __float_as_uint(f);
    unsigned r = (u + 0x7fffu + ((u >> 16) & 1u)) >> 16;
    return (short)r;
}

// ---------------- f32 -> bf16 convert ----------------
__global__ void f2b_k(const float* __restrict__ in, short* __restrict__ out, int n) {
    int i = blockIdx.x * 256 + threadIdx.x;
    if (i < n) out[i] = f2b(in[i]);
}

// ---------------- patch embed: tok[b,s,d] (f32) ----------------
__global__ void patch_embed_k(const float* __restrict__ x, const float* __restrict__ cw,
                              const float* __restrict__ cb, const float* __restrict__ cls,
                              const float* __restrict__ pos, float* __restrict__ tok) {
    int bs = blockIdx.x;
    int b = bs / Sz, s = bs % Sz;
    int d = threadIdx.x;
    __shared__ float xp[Pz];
    if (s == 0) {
        if (d < Dz) tok[(size_t)bs * Dz + d] = cls[d] + pos[d];
        return;
    }
    if (d < Pz) xp[d] = x[(size_t)b * Tz + (s - 1) * Pz + d];
    __syncthreads();
    if (d < Dz) {
        float acc = cb[d];
        const float* w = cw + d * Pz;
        #pragma unroll
        for (int p = 0; p < Pz; ++p) acc += xp[p] * w[p];
        tok[(size_t)bs * Dz + d] = acc + pos[s * Dz + d];
    }
}

// ---------------- layernorm: f32 in -> bf16 out ----------------
__global__ void ln_k(const float* __restrict__ in, short* __restrict__ out,
                     const float* __restrict__ sc, const float* __restrict__ bi, int rows) {
    int wave = threadIdx.x >> 6, lane = threadIdx.x & 63;
    int row = blockIdx.x * 4 + wave;
    if (row >= rows) return;
    const float* x = in + (size_t)row * Dz;
    float v[4];
    float sum = 0.f;
    #pragma unroll
    for (int i = 0; i < 4; ++i) {
        int d = lane + 64 * i;
        v[i] = (d < Dz) ? x[d] : 0.f;
        sum += v[i];
    }
    #pragma unroll
    for (int off = 32; off; off >>= 1) sum += __shfl_xor(sum, off);
    float mean = sum * (1.f / Dz);
    float var = 0.f;
    #pragma unroll
    for (int i = 0; i < 4; ++i) {
        int d = lane + 64 * i;
        if (d < Dz) { float t = v[i] - mean; var += t * t; }
    }
    #pragma unroll
    for (int off = 32; off; off >>= 1) var += __shfl_xor(var, off);
    var *= (1.f / Dz);
    float rstd = rsqrtf(var + 1e-6f);
    short* o = out + (size_t)row * Dz;
    #pragma unroll
    for (int i = 0; i < 4; ++i) {
        int d = lane + 64 * i;
        if (d < Dz) o[d] = f2b((v[i] - mean) * rstd * sc[d] + bi[d]);
    }
}

// ---------------- MFMA GEMM: out[M,N] = A[M,K](bf16) @ W[N,K](bf16)^T + epilogue ----------------
#define BMt 128
#define BNt 64
#define LDT 40
template <int MODE>
__global__ __launch_bounds__(256) void mfma_gemm_k(
        const short* __restrict__ A, const short* __restrict__ W,
        const float* __restrict__ bias, const float* __restrict__ bias2,
        const float* __restrict__ res, void* __restrict__ outv,
        int M, int N, int K) {
    __shared__ short As[BMt * LDT];
    __shared__ short Ws[BNt * LDT];
    const int t = threadIdx.x;
    const int lane = t & 63, wid = t >> 6;
    const int wm = wid & 1, wn = wid >> 1;      // 2x2 wave grid
    const int row0 = blockIdx.y * BMt, col0 = blockIdx.x * BNt;
    const int l15 = lane & 15, l4 = lane >> 4;

    f32x4 acc[4][2];
    #pragma unroll
    for (int mi = 0; mi < 4; ++mi)
        #pragma unroll
        for (int nj = 0; nj < 2; ++nj) {
            f32x4 z = {0.f, 0.f, 0.f, 0.f};
            acc[mi][nj] = z;
        }

    const int nk = (K + 31) >> 5;
    for (int kt = 0; kt < nk; ++kt) {
        int k0 = kt * 32;
        #pragma unroll
        for (int i = 0; i < 2; ++i) {
            int e = t + i * 256;
            int r = e >> 2, c = e & 3;
            int gm = row0 + r, gk = k0 + c * 8;
            bf16x8 v = {0, 0, 0, 0, 0, 0, 0, 0};
            if (gm < M && gk + 8 <= K) v = *(const bf16x8*)(A + (size_t)gm * K + gk);
            *(bf16x8*)(As + r * LDT + c * 8) = v;
        }
        {
            int r = t >> 2, c = t & 3;
            int gn = col0 + r, gk = k0 + c * 8;
            bf16x8 v = {0, 0, 0, 0, 0, 0, 0, 0};
            if (gn < N && gk + 8 <= K) v = *(const bf16x8*)(W + (size_t)gn * K + gk);
            *(bf16x8*)(Ws + r * LDT + c * 8) = v;
        }
        __syncthreads();
        bf16x8 bfrag[2];
        #pragma unroll
        for (int nj = 0; nj < 2; ++nj)
            bfrag[nj] = *(const bf16x8*)(Ws + (wn * 32 + nj * 16 + l15) * LDT + l4 * 8);
        #pragma unroll
        for (int mi = 0; mi < 4; ++mi) {
            bf16x8 afrag = *(const bf16x8*)(As + (wm * 64 + mi * 16 + l15) * LDT + l4 * 8);
            #pragma unroll
            for (int nj = 0; nj < 2; ++nj)
                acc[mi][nj] = __builtin_amdgcn_mfma_f32_16x16x32_bf16(afrag, bfrag[nj], acc[mi][nj], 0, 0, 0);
        }
        __syncthreads();
    }

    #pragma unroll
    for (int mi = 0; mi < 4; ++mi) {
        #pragma unroll
        for (int nj = 0; nj < 2; ++nj) {
            #pragma unroll
            for (int r = 0; r < 4; ++r) {
                int m = row0 + wm * 64 + mi * 16 + l4 * 4 + r;
                int n = col0 + wn * 32 + nj * 16 + l15;
                if (m >= M || n >= N) continue;
                float v = acc[mi][nj][r];
                size_t off = (size_t)m * N + n;
                if (MODE == 0) {
                    ((float*)outv)[off] = v + bias[n];
                } else if (MODE == 1) {
                    v += (n < Dz) ? bias[n] : ((n >= 2 * Dz) ? bias2[n - 2 * Dz] : 0.f);
                    ((float*)outv)[off] = v;
                } else if (MODE == 2) {
                    ((float*)outv)[off] = v + bias[n] + res[off];
                } else {
                    v += bias[n];
                    v = 0.5f * v * (1.f + erff(v * 0.70710678118654752f));
                    ((short*)outv)[off] = f2b(v);
                }
            }
        }
    }
}

// ---------------- attention v2: 512 thr, 2-way j-split, defer-max, float4 LDS ----------------
__global__ __launch_bounds__(512) void attn2_k(const float* __restrict__ qkv,
                                               const float* __restrict__ rpb,
                                               short* __restrict__ o) {
    int b = blockIdx.x / Hz, h = blockIdx.x % Hz;
    __shared__ float Kl[Sz * HDz];
    __shared__ float Vl[Sz * HDz];
    __shared__ float Bb[NRDz];
    __shared__ float Mm[256];
    __shared__ float Llv[256];
    const float* base = qkv + (size_t)b * Sz * (3 * Dz);
    int t = threadIdx.x;
    for (int idx = t; idx < Sz * HDz; idx += 512) {
        int s = idx / HDz, d = idx - s * HDz;
        Kl[idx] = base[(size_t)s * (3 * Dz) + Dz + h * HDz + d];
        Vl[idx] = base[(size_t)s * (3 * Dz) + 2 * Dz + h * HDz + d];
    }
    for (int idx = t; idx < NRDz; idx += 512) Bb[idx] = rpb[idx * Hz + h];
    __syncthreads();

    const int r = t & 255, jh = t >> 8;
    const bool act = r < Sz;
    float q[HDz];
    if (act) {
        const float* qp = base + (size_t)r * (3 * Dz) + h * HDz;
        #pragma unroll
        for (int d = 0; d < HDz; ++d) q[d] = qp[d] * SCALEq;
    } else {
        #pragma unroll
        for (int d = 0; d < HDz; ++d) q[d] = 0.f;
    }

    float m = -1e30f, l = 0.f;
    float acc[HDz];
    #pragma unroll
    for (int d = 0; d < HDz; ++d) acc[d] = 0.f;

    const int j0 = jh * 121, j1 = jh ? Sz : 121;
    for (int j = j0; j < j1; ++j) {
        float s;
        if (r == 0)      s = (j == 0) ? Bb[NRDz - 1] : Bb[NRDz - 3];
        else if (j == 0) s = Bb[NRDz - 2];
        else             s = Bb[r - j + (Nz - 1)];
        const f32x4* kr = (const f32x4*)(Kl + j * HDz);
        #pragma unroll
        for (int c = 0; c < 5; ++c) {
            f32x4 kv = kr[c];
            s += q[c * 4 + 0] * kv[0] + q[c * 4 + 1] * kv[1]
               + q[c * 4 + 2] * kv[2] + q[c * 4 + 3] * kv[3];
        }
        if (!act) s = 0.f;
        const f32x4* vr = (const f32x4*)(Vl + j * HDz);
        if (__all(s - m <= 8.f)) {          // deferred-max fast path
            float p = __expf(s - m);
            l += p;
            #pragma unroll
            for (int c = 0; c < 5; ++c) {
                f32x4 vv = vr[c];
                acc[c * 4 + 0] += p * vv[0]; acc[c * 4 + 1] += p * vv[1];
                acc[c * 4 + 2] += p * vv[2]; acc[c * 4 + 3] += p * vv[3];
            }
        } else {
            float mn = fmaxf(m, s);
            float sc = __expf(m - mn);
            float p = __expf(s - mn);
            l = l * sc + p;
            #pragma unroll
            for (int c = 0; c < 5; ++c) {
                f32x4 vv = vr[c];
                acc[c * 4 + 0] = acc[c * 4 + 0] * sc + p * vv[0];
                acc[c * 4 + 1] = acc[c * 4 + 1] * sc + p * vv[1];
                acc[c * 4 + 2] = acc[c * 4 + 2] * sc + p * vv[2];
                acc[c * 4 + 3] = acc[c * 4 + 3] * sc + p * vv[3];
            }
            m = mn;
        }
    }

    __syncthreads();                 // all reads of Kl/Vl done
    if (jh == 1 && act) {
        Mm[r] = m; Llv[r] = l;
        #pragma unroll
        for (int d = 0; d < HDz; ++d) Kl[r * HDz + d] = acc[d];   // reuse K buffer
    }
    __syncthreads();
    if (jh == 0 && act) {
        float m2 = Mm[r], l2 = Llv[r];
        float mn = fmaxf(m, m2);
        float s1 = __expf(m - mn), s2 = __expf(m2 - mn);
        float L = l * s1 + l2 * s2;
        float inv = 1.f / L;
        short* op = o + ((size_t)b * Sz + r) * Dz + h * HDz;
        #pragma unroll
        for (int d = 0; d < HDz; ++d)
            op[d] = f2b((acc[d] * s1 + Kl[r * HDz + d] * s2) * inv);
    }
}

// ---------------- pool + fc_norm -> bf16 pooled ----------------
__global__ void pool_norm_k(const float* __restrict__ tok, const float* __restrict__ sc,
                            const float* __restrict__ bi, short* __restrict__ pooled) {
    int b = blockIdx.x;
    int t = threadIdx.x;
    float val = 0.f;
    if (t < Dz) {
        const float* base = tok + ((size_t)b * Sz + 1) * Dz + t;
        float s = 0.f;
        for (int si = 0; si < Nz; ++si) s += base[(size_t)si * Dz];
        val = s * (1.f / Nz);
    }
    __shared__ float red[8];
    float sum = val, sq = val * val;
    #pragma unroll
    for (int off = 32; off; off >>= 1) { sum += __shfl_xor(sum, off); sq += __shfl_xor(sq, off); }
    int wave = t >> 6, lane = t & 63;
    if (lane == 0) { red[wave] = sum; red[4 + wave] = sq; }
    __syncthreads();
    sum = red[0] + red[1] + red[2] + red[3];
    sq = red[4] + red[5] + red[6] + red[7];
    float mean = sum * (1.f / Dz);
    float var = sq * (1.f / Dz) - mean * mean;
    float rstd = rsqrtf(var + 1e-6f);
    if (t < Dz) pooled[(size_t)b * Dz + t] = f2b((val - mean) * rstd * sc[t] + bi[t]);
}

extern "C" void kernel_launch(void* const* d_in, const int* in_sizes, int n_in,
                              void* d_out, int out_size, void* d_ws, size_t ws_size,
                              hipStream_t stream) {
    const float* x        = (const float*)d_in[0];
    const float* conv_w   = (const float*)d_in[1];
    const float* conv_b   = (const float*)d_in[2];
    const float* cls_tok  = (const float*)d_in[3];
    const float* pos_emb  = (const float*)d_in[4];
    const float* ln1_s    = (const float*)d_in[5];
    const float* ln1_b    = (const float*)d_in[6];
    const float* qkv_w    = (const float*)d_in[7];
    const float* q_bias   = (const float*)d_in[8];
    const float* v_bias   = (const float*)d_in[9];
    const float* rpb      = (const float*)d_in[10];
    const float* proj_w   = (const float*)d_in[11];
    const float* proj_b   = (const float*)d_in[12];
    const float* ln2_s    = (const float*)d_in[13];
    const float* ln2_b    = (const float*)d_in[14];
    const float* fc1_w    = (const float*)d_in[15];
    const float* fc1_b    = (const float*)d_in[16];
    const float* fc2_w    = (const float*)d_in[17];
    const float* fc2_b    = (const float*)d_in[18];
    const float* fcn_s    = (const float*)d_in[19];
    const float* fcn_b    = (const float*)d_in[20];
    const float* head_w   = (const float*)d_in[21];
    const float* head_b   = (const float*)d_in[22];
    float* out = (float*)d_out;

    char* ws = (char*)d_ws;
    float* tok    = (float*)ws;                               ws += (size_t)BS * Dz * 4;
    short* xln    = (short*)ws;                               ws += (size_t)BS * Dz * 2;
    float* qkvbuf = (float*)ws;                               // BS*600 f32
    short* mid    = (short*)ws;                               // alias: BS*800 bf16
    ws += (size_t)BS * 3 * Dz * 4;
    short* wq = (short*)ws;   ws += (size_t)Lz * 3 * Dz * Dz * 2;
    short* wp = (short*)ws;   ws += (size_t)Lz * Dz * Dz * 2;
    short* w1 = (short*)ws;   ws += (size_t)Lz * FFz * Dz * 2;
    short* w2 = (short*)ws;   ws += (size_t)Lz * Dz * FFz * 2;
    short* wh = (short*)ws;   ws += (size_t)NCz * Dz * 2;
    short* pooledb = (short*)ws;

    {
        int n;
        n = Lz * 3 * Dz * Dz; f2b_k<<<(n + 255) / 256, 256, 0, stream>>>(qkv_w, wq, n);
        n = Lz * Dz * Dz;     f2b_k<<<(n + 255) / 256, 256, 0, stream>>>(proj_w, wp, n);
        n = Lz * FFz * Dz;    f2b_k<<<(n + 255) / 256, 256, 0, stream>>>(fc1_w, w1, n);
        n = Lz * Dz * FFz;    f2b_k<<<(n + 255) / 256, 256, 0, stream>>>(fc2_w, w2, n);
        n = NCz * Dz;         f2b_k<<<(n + 255) / 256, 256, 0, stream>>>(head_w, wh, n);
    }

    patch_embed_k<<<BS, 256, 0, stream>>>(x, conv_w, conv_b, cls_tok, pos_emb, tok);

    dim3 blk(256);
    const int MT = (BS + BMt - 1) / BMt;   // 121
    for (int l = 0; l < Lz; ++l) {
        ln_k<<<(BS + 3) / 4, blk, 0, stream>>>(tok, xln, ln1_s + l * Dz, ln1_b + l * Dz, BS);
        mfma_gemm_k<1><<<dim3((3 * Dz + BNt - 1) / BNt, MT), blk, 0, stream>>>(
            xln, wq + (size_t)l * 3 * Dz * Dz, q_bias + l * Dz, v_bias + l * Dz,
            nullptr, qkvbuf, BS, 3 * Dz, Dz);
        attn2_k<<<Bz * Hz, dim3(512), 0, stream>>>(qkvbuf, rpb + (size_t)l * NRDz * Hz, xln);
        mfma_gemm_k<2><<<dim3((Dz + BNt - 1) / BNt, MT), blk, 0, stream>>>(
            xln, wp + (size_t)l * Dz * Dz, proj_b + l * Dz, nullptr,
            tok, tok, BS, Dz, Dz);
        ln_k<<<(BS + 3) / 4, blk, 0, stream>>>(tok, xln, ln2_s + l * Dz, ln2_b + l * Dz, BS);
        mfma_gemm_k<3><<<dim3((FFz + BNt - 1) / BNt, MT), blk, 0, stream>>>(
            xln, w1 + (size_t)l * FFz * Dz, fc1_b + l * FFz, nullptr,
            nullptr, mid, BS, FFz, Dz);
        mfma_gemm_k<2><<<dim3((Dz + BNt - 1) / BNt, MT), blk, 0, stream>>>(
            mid, w2 + (size_t)l * Dz * FFz, fc2_b + l * Dz, nullptr,
            tok, tok, BS, Dz, FFz);
    }

    pool_norm_k<<<Bz, blk, 0, stream>>>(tok, fcn_s, fcn_b, pooledb);
    mfma_gemm_k<0><<<dim3((NCz + BNt - 1) / BNt, 1), blk, 0, stream>>>(
        pooledb, wh, head_b, nullptr, nullptr, out, Bz, NCz, Dz);
}

// Round 4
// 2709.298 us; speedup vs baseline: 1.1498x; 1.1498x over previous
//
#include <hip/hip_runtime.h>
#include <math.h>

#define Bz 64
#define Tz 12000
#define Pz 50
#define Dz 200
#define Lz 12
#define Hz 10
#define HDz 20
#define FFz 800
#define Nz 240
#define Sz 241
#define NRDz 482
#define NCz 1000
#define BS (Bz * Sz)          // 15424
#define SCALEq 0.22360679774997896f

typedef __attribute__((ext_vector_type(8))) short bf16x8;
typedef __attribute__((ext_vector_type(4))) float f32x4;

static __device__ __forceinline__ short f2b(float f) {
    unsigned u = __float_as_uint(f);
    unsigned r = (u + 0x7fffu + ((u >> 16) & 1u)) >> 16;
    return (short)r;
}

// ---------------- f32 -> bf16 convert ----------------
__global__ void f2b_k(const float* __restrict__ in, short* __restrict__ out, int n) {
    int i = blockIdx.x * 256 + threadIdx.x;
    if (i < n) out[i] = f2b(in[i]);
}

// ---------------- patch embed: tok[b,s,d] (f32) ----------------
__global__ void patch_embed_k(const float* __restrict__ x, const float* __restrict__ cw,
                              const float* __restrict__ cb, const float* __restrict__ cls,
                              const float* __restrict__ pos, float* __restrict__ tok) {
    int bs = blockIdx.x;
    int b = bs / Sz, s = bs % Sz;
    int d = threadIdx.x;
    __shared__ float xp[Pz];
    if (s == 0) {
        if (d < Dz) tok[(size_t)bs * Dz + d] = cls[d] + pos[d];
        return;
    }
    if (d < Pz) xp[d] = x[(size_t)b * Tz + (s - 1) * Pz + d];
    __syncthreads();
    if (d < Dz) {
        float acc = cb[d];
        const float* w = cw + d * Pz;
        #pragma unroll
        for (int p = 0; p < Pz; ++p) acc += xp[p] * w[p];
        tok[(size_t)bs * Dz + d] = acc + pos[s * Dz + d];
    }
}

// ---------------- layernorm: f32 in -> bf16 out ----------------
__global__ void ln_k(const float* __restrict__ in, short* __restrict__ out,
                     const float* __restrict__ sc, const float* __restrict__ bi, int rows) {
    int wave = threadIdx.x >> 6, lane = threadIdx.x & 63;
    int row = blockIdx.x * 4 + wave;
    if (row >= rows) return;
    const float* x = in + (size_t)row * Dz;
    float v[4];
    float sum = 0.f;
    #pragma unroll
    for (int i = 0; i < 4; ++i) {
        int d = lane + 64 * i;
        v[i] = (d < Dz) ? x[d] : 0.f;
        sum += v[i];
    }
    #pragma unroll
    for (int off = 32; off; off >>= 1) sum += __shfl_xor(sum, off);
    float mean = sum * (1.f / Dz);
    float var = 0.f;
    #pragma unroll
    for (int i = 0; i < 4; ++i) {
        int d = lane + 64 * i;
        if (d < Dz) { float t = v[i] - mean; var += t * t; }
    }
    #pragma unroll
    for (int off = 32; off; off >>= 1) var += __shfl_xor(var, off);
    var *= (1.f / Dz);
    float rstd = rsqrtf(var + 1e-6f);
    short* o = out + (size_t)row * Dz;
    #pragma unroll
    for (int i = 0; i < 4; ++i) {
        int d = lane + 64 * i;
        if (d < Dz) o[d] = f2b((v[i] - mean) * rstd * sc[d] + bi[d]);
    }
}

// ---------------- MFMA GEMM: out[M,N] = A[M,K](bf16) @ W[N,K](bf16)^T + epilogue ----------------
// MODE 0: f32 out = acc + bias                   (head)
// MODE 1: bf16 out = acc + (q_bias|0|v_bias)     (qkv)
// MODE 2: f32 out = acc + bias + res             (proj/fc2 residual)
// MODE 3: bf16 out = gelu(acc + bias)            (fc1)
#define BMt 128
#define BNt 64
#define LDT 40
template <int MODE>
__global__ __launch_bounds__(256) void mfma_gemm_k(
        const short* __restrict__ A, const short* __restrict__ W,
        const float* __restrict__ bias, const float* __restrict__ bias2,
        const float* __restrict__ res, void* __restrict__ outv,
        int M, int N, int K) {
    __shared__ short As[BMt * LDT];
    __shared__ short Ws[BNt * LDT];
    const int t = threadIdx.x;
    const int lane = t & 63, wid = t >> 6;
    const int wm = wid & 1, wn = wid >> 1;      // 2x2 wave grid
    const int row0 = blockIdx.y * BMt, col0 = blockIdx.x * BNt;
    const int l15 = lane & 15, l4 = lane >> 4;

    f32x4 acc[4][2];
    #pragma unroll
    for (int mi = 0; mi < 4; ++mi)
        #pragma unroll
        for (int nj = 0; nj < 2; ++nj) {
            f32x4 z = {0.f, 0.f, 0.f, 0.f};
            acc[mi][nj] = z;
        }

    const int nk = (K + 31) >> 5;
    for (int kt = 0; kt < nk; ++kt) {
        int k0 = kt * 32;
        #pragma unroll
        for (int i = 0; i < 2; ++i) {
            int e = t + i * 256;
            int r = e >> 2, c = e & 3;
            int gm = row0 + r, gk = k0 + c * 8;
            bf16x8 v = {0, 0, 0, 0, 0, 0, 0, 0};
            if (gm < M && gk + 8 <= K) v = *(const bf16x8*)(A + (size_t)gm * K + gk);
            *(bf16x8*)(As + r * LDT + c * 8) = v;
        }
        {
            int r = t >> 2, c = t & 3;
            int gn = col0 + r, gk = k0 + c * 8;
            bf16x8 v = {0, 0, 0, 0, 0, 0, 0, 0};
            if (gn < N && gk + 8 <= K) v = *(const bf16x8*)(W + (size_t)gn * K + gk);
            *(bf16x8*)(Ws + r * LDT + c * 8) = v;
        }
        __syncthreads();
        bf16x8 bfrag[2];
        #pragma unroll
        for (int nj = 0; nj < 2; ++nj)
            bfrag[nj] = *(const bf16x8*)(Ws + (wn * 32 + nj * 16 + l15) * LDT + l4 * 8);
        #pragma unroll
        for (int mi = 0; mi < 4; ++mi) {
            bf16x8 afrag = *(const bf16x8*)(As + (wm * 64 + mi * 16 + l15) * LDT + l4 * 8);
            #pragma unroll
            for (int nj = 0; nj < 2; ++nj)
                acc[mi][nj] = __builtin_amdgcn_mfma_f32_16x16x32_bf16(afrag, bfrag[nj], acc[mi][nj], 0, 0, 0);
        }
        __syncthreads();
    }

    #pragma unroll
    for (int mi = 0; mi < 4; ++mi) {
        #pragma unroll
        for (int nj = 0; nj < 2; ++nj) {
            #pragma unroll
            for (int r = 0; r < 4; ++r) {
                int m = row0 + wm * 64 + mi * 16 + l4 * 4 + r;
                int n = col0 + wn * 32 + nj * 16 + l15;
                if (m >= M || n >= N) continue;
                float v = acc[mi][nj][r];
                size_t off = (size_t)m * N + n;
                if (MODE == 0) {
                    ((float*)outv)[off] = v + bias[n];
                } else if (MODE == 1) {
                    v += (n < Dz) ? bias[n] : ((n >= 2 * Dz) ? bias2[n - 2 * Dz] : 0.f);
                    ((short*)outv)[off] = f2b(v);
                } else if (MODE == 2) {
                    ((float*)outv)[off] = v + bias[n] + res[off];
                } else {
                    v += bias[n];
                    v = 0.5f * v * (1.f + erff(v * 0.70710678118654752f));
                    ((short*)outv)[off] = f2b(v);
                }
            }
        }
    }
}

// ---------------- MFMA attention ----------------
// qkv: bf16 [BS][600]; o: bf16 [BS][200]. One block per (b,h); 4 waves x 64 q-rows.
#define KSLD 40   // K LDS row stride (shorts)
#define PLD  40   // P LDS row stride (shorts)
__global__ __launch_bounds__(256) void attn_mfma_k(const short* __restrict__ qkv,
                                                   const float* __restrict__ rpb,
                                                   short* __restrict__ o) {
    const int b = blockIdx.x / Hz, h = blockIdx.x % Hz;
    __shared__ short Ks[256 * KSLD];        // 20 KB, rows kcol, cols d (20 real + pad zeros)
    __shared__ short Vt[32 * 256];          // 16 KB, rows d, cols kcol, XOR-swizzled
    __shared__ short Pl[4][64 * PLD];       // 20 KB, per-wave P half-tile
    __shared__ float Bb[NRDz + 2];
    const int t = threadIdx.x;
    const int lane = t & 63, w = t >> 6;
    const int l15 = lane & 15, lg = lane >> 4;
    const size_t brow = (size_t)b * Sz;

    // phase 1: zero Vt (garbage cols would NaN-poison PV via 0*Inf)
    {
        f32x4 z = {0.f, 0.f, 0.f, 0.f};
        f32x4* vz = (f32x4*)Vt;
        #pragma unroll
        for (int i = 0; i < 4; ++i) vz[t * 4 + i] = z;
    }
    __syncthreads();

    // phase 2: stage Bb, Ks (zero-padded), Vt (transposed, swizzled)
    for (int i = t; i < NRDz; i += 256) Bb[i] = rpb[i * Hz + h];
    {
        const int s = t;
        short4 kv[5], vv[5];
        short4 z4 = {0, 0, 0, 0};
        if (s < Sz) {
            const short* kp = qkv + (brow + s) * 600 + Dz + h * HDz;
            const short* vp = qkv + (brow + s) * 600 + 2 * Dz + h * HDz;
            #pragma unroll
            for (int c = 0; c < 5; ++c) {
                kv[c] = *(const short4*)(kp + c * 4);
                vv[c] = *(const short4*)(vp + c * 4);
            }
        } else {
            #pragma unroll
            for (int c = 0; c < 5; ++c) { kv[c] = z4; vv[c] = z4; }
        }
        #pragma unroll
        for (int c = 0; c < 5; ++c) *(short4*)(Ks + s * KSLD + c * 4) = kv[c];
        #pragma unroll
        for (int c = 5; c < 10; ++c) *(short4*)(Ks + s * KSLD + c * 4) = z4;
        if (s < Sz) {
            char* vb = (char*)Vt;
            const short* vs = (const short*)vv;
            #pragma unroll
            for (int d = 0; d < HDz; ++d) {
                int addr = d * 512 + ((s * 2) ^ ((d & 7) << 4));
                *(short*)(vb + addr) = vs[d];
            }
        }
    }

    // Q fragments from global (zero-padded d>=20)
    bf16x8 qfrag[4];
    #pragma unroll
    for (int mi = 0; mi < 4; ++mi) {
        int q = 64 * w + 16 * mi + l15;
        const short* qp = qkv + (brow + q) * 600 + h * HDz + lg * 8;
        short4 lo = {0, 0, 0, 0}, hi = {0, 0, 0, 0};
        if (lg < 3) lo = *(const short4*)qp;
        if (lg < 2) hi = *(const short4*)(qp + 4);
        bf16x8 f;
        f[0] = lo.x; f[1] = lo.y; f[2] = lo.z; f[3] = lo.w;
        f[4] = hi.x; f[5] = hi.y; f[6] = hi.z; f[7] = hi.w;
        qfrag[mi] = f;
    }
    __syncthreads();

    const float B479 = Bb[NRDz - 3], B480 = Bb[NRDz - 2], B481 = Bb[NRDz - 1];
    f32x4 O[4][2], mrow[4], lrow[4];
    {
        f32x4 z = {0.f, 0.f, 0.f, 0.f};
        f32x4 mneg = {-1e30f, -1e30f, -1e30f, -1e30f};
        #pragma unroll
        for (int mi = 0; mi < 4; ++mi) {
            O[mi][0] = z; O[mi][1] = z;
            mrow[mi] = mneg; lrow[mi] = z;
        }
    }

    #pragma unroll 1
    for (int kc = 0; kc < 4; ++kc) {
        // K fragments
        bf16x8 kf[4];
        #pragma unroll
        for (int nj = 0; nj < 4; ++nj)
            kf[nj] = *(const bf16x8*)(Ks + (kc * 64 + nj * 16 + l15) * KSLD + lg * 8);
        // QK^T
        f32x4 s[4][4];
        #pragma unroll
        for (int mi = 0; mi < 4; ++mi)
            #pragma unroll
            for (int nj = 0; nj < 4; ++nj) {
                f32x4 z = {0.f, 0.f, 0.f, 0.f};
                s[mi][nj] = __builtin_amdgcn_mfma_f32_16x16x32_bf16(qfrag[mi], kf[nj], z, 0, 0, 0);
            }
        // scale + bias + mask  (C layout: row q = 4*lg+r, col kcol = l15)
        #pragma unroll
        for (int mi = 0; mi < 4; ++mi) {
            int q0 = 64 * w + 16 * mi + 4 * lg;
            #pragma unroll
            for (int nj = 0; nj < 4; ++nj) {
                int kcol = kc * 64 + nj * 16 + l15;
                #pragma unroll
                for (int r = 0; r < 4; ++r) {
                    int q = q0 + r;
                    int idx = q - kcol + (Nz - 1);
                    idx = idx < 0 ? 0 : (idx > NRDz - 1 ? NRDz - 1 : idx);
                    float bv = Bb[idx];
                    if (q == 0) bv = B479;
                    if (kcol == 0) bv = (q == 0) ? B481 : B480;
                    if (kcol > Nz || q > Nz) bv = -1e30f;
                    s[mi][nj][r] = s[mi][nj][r] * SCALEq + bv;
                }
            }
        }
        // online softmax per row group
        #pragma unroll
        for (int mi = 0; mi < 4; ++mi) {
            f32x4 pm;
            #pragma unroll
            for (int c = 0; c < 4; ++c)
                pm[c] = fmaxf(fmaxf(s[mi][0][c], s[mi][1][c]), fmaxf(s[mi][2][c], s[mi][3][c]));
            #pragma unroll
            for (int msk = 1; msk <= 8; msk <<= 1)
                #pragma unroll
                for (int c = 0; c < 4; ++c) pm[c] = fmaxf(pm[c], __shfl_xor(pm[c], msk));
            f32x4 mn, sc;
            #pragma unroll
            for (int c = 0; c < 4; ++c) {
                mn[c] = fmaxf(mrow[mi][c], pm[c]);
                sc[c] = __expf(mrow[mi][c] - mn[c]);
            }
            mrow[mi] = mn;
            f32x4 ls = {0.f, 0.f, 0.f, 0.f};
            #pragma unroll
            for (int nj = 0; nj < 4; ++nj) {
                #pragma unroll
                for (int c = 0; c < 4; ++c) s[mi][nj][c] = __expf(s[mi][nj][c] - mn[c]);
                ls += s[mi][nj];
            }
            #pragma unroll
            for (int msk = 1; msk <= 8; msk <<= 1)
                #pragma unroll
                for (int c = 0; c < 4; ++c) ls[c] += __shfl_xor(ls[c], msk);
            lrow[mi] = lrow[mi] * sc + ls;
            O[mi][0] *= sc;
            O[mi][1] *= sc;
        }
        // PV in two K=32 halves through per-wave P tile
        #pragma unroll
        for (int kk = 0; kk < 2; ++kk) {
            #pragma unroll
            for (int mi = 0; mi < 4; ++mi)
                #pragma unroll
                for (int njh = 0; njh < 2; ++njh) {
                    int nj = kk * 2 + njh;
                    #pragma unroll
                    for (int r = 0; r < 4; ++r)
                        Pl[w][(mi * 16 + 4 * lg + r) * PLD + njh * 16 + l15] = f2b(s[mi][nj][r]);
                }
            bf16x8 vf[2];
            #pragma unroll
            for (int dj = 0; dj < 2; ++dj) {
                int d = dj * 16 + l15;
                int cb = (kc * 128 + kk * 64 + lg * 16) ^ ((l15 & 7) << 4);
                vf[dj] = *(const bf16x8*)((const char*)Vt + d * 512 + cb);
            }
            #pragma unroll
            for (int mi = 0; mi < 4; ++mi) {
                bf16x8 af = *(const bf16x8*)(Pl[w] + (mi * 16 + l15) * PLD + lg * 8);
                O[mi][0] = __builtin_amdgcn_mfma_f32_16x16x32_bf16(af, vf[0], O[mi][0], 0, 0, 0);
                O[mi][1] = __builtin_amdgcn_mfma_f32_16x16x32_bf16(af, vf[1], O[mi][1], 0, 0, 0);
            }
        }
    }

    // epilogue
    #pragma unroll
    for (int mi = 0; mi < 4; ++mi) {
        f32x4 inv;
        #pragma unroll
        for (int c = 0; c < 4; ++c) inv[c] = 1.f / lrow[mi][c];
        #pragma unroll
        for (int dj = 0; dj < 2; ++dj) {
            int d = dj * 16 + l15;
            if (d >= HDz) continue;
            #pragma unroll
            for (int r = 0; r < 4; ++r) {
                int q = 64 * w + 16 * mi + 4 * lg + r;
                if (q < Sz)
                    o[(brow + q) * Dz + h * HDz + d] = f2b(O[mi][dj][r] * inv[r]);
            }
        }
    }
}

// ---------------- pool + fc_norm -> bf16 pooled ----------------
__global__ void pool_norm_k(const float* __restrict__ tok, const float* __restrict__ sc,
                            const float* __restrict__ bi, short* __restrict__ pooled) {
    int b = blockIdx.x;
    int t = threadIdx.x;
    float val = 0.f;
    if (t < Dz) {
        const float* base = tok + ((size_t)b * Sz + 1) * Dz + t;
        float s = 0.f;
        for (int si = 0; si < Nz; ++si) s += base[(size_t)si * Dz];
        val = s * (1.f / Nz);
    }
    __shared__ float red[8];
    float sum = val, sq = val * val;
    #pragma unroll
    for (int off = 32; off; off >>= 1) { sum += __shfl_xor(sum, off); sq += __shfl_xor(sq, off); }
    int wave = t >> 6, lane = t & 63;
    if (lane == 0) { red[wave] = sum; red[4 + wave] = sq; }
    __syncthreads();
    sum = red[0] + red[1] + red[2] + red[3];
    sq = red[4] + red[5] + red[6] + red[7];
    float mean = sum * (1.f / Dz);
    float var = sq * (1.f / Dz) - mean * mean;
    float rstd = rsqrtf(var + 1e-6f);
    if (t < Dz) pooled[(size_t)b * Dz + t] = f2b((val - mean) * rstd * sc[t] + bi[t]);
}

extern "C" void kernel_launch(void* const* d_in, const int* in_sizes, int n_in,
                              void* d_out, int out_size, void* d_ws, size_t ws_size,
                              hipStream_t stream) {
    const float* x        = (const float*)d_in[0];
    const float* conv_w   = (const float*)d_in[1];
    const float* conv_b   = (const float*)d_in[2];
    const float* cls_tok  = (const float*)d_in[3];
    const float* pos_emb  = (const float*)d_in[4];
    const float* ln1_s    = (const float*)d_in[5];
    const float* ln1_b    = (const float*)d_in[6];
    const float* qkv_w    = (const float*)d_in[7];
    const float* q_bias   = (const float*)d_in[8];
    const float* v_bias   = (const float*)d_in[9];
    const float* rpb      = (const float*)d_in[10];
    const float* proj_w   = (const float*)d_in[11];
    const float* proj_b   = (const float*)d_in[12];
    const float* ln2_s    = (const float*)d_in[13];
    const float* ln2_b    = (const float*)d_in[14];
    const float* fc1_w    = (const float*)d_in[15];
    const float* fc1_b    = (const float*)d_in[16];
    const float* fc2_w    = (const float*)d_in[17];
    const float* fc2_b    = (const float*)d_in[18];
    const float* fcn_s    = (const float*)d_in[19];
    const float* fcn_b    = (const float*)d_in[20];
    const float* head_w   = (const float*)d_in[21];
    const float* head_b   = (const float*)d_in[22];
    float* out = (float*)d_out;

    char* ws = (char*)d_ws;
    float* tok  = (float*)ws;                               ws += (size_t)BS * Dz * 4;
    short* xln  = (short*)ws;                               ws += (size_t)BS * Dz * 2;
    short* qkvb = (short*)ws;                               // BS*600 bf16
    short* mid  = (short*)ws;                               // alias: BS*800 bf16 (larger)
    ws += (size_t)BS * FFz * 2;
    short* wq = (short*)ws;   ws += (size_t)Lz * 3 * Dz * Dz * 2;
    short* wp = (short*)ws;   ws += (size_t)Lz * Dz * Dz * 2;
    short* w1 = (short*)ws;   ws += (size_t)Lz * FFz * Dz * 2;
    short* w2 = (short*)ws;   ws += (size_t)Lz * Dz * FFz * 2;
    short* wh = (short*)ws;   ws += (size_t)NCz * Dz * 2;
    short* pooledb = (short*)ws;

    {
        int n;
        n = Lz * 3 * Dz * Dz; f2b_k<<<(n + 255) / 256, 256, 0, stream>>>(qkv_w, wq, n);
        n = Lz * Dz * Dz;     f2b_k<<<(n + 255) / 256, 256, 0, stream>>>(proj_w, wp, n);
        n = Lz * FFz * Dz;    f2b_k<<<(n + 255) / 256, 256, 0, stream>>>(fc1_w, w1, n);
        n = Lz * Dz * FFz;    f2b_k<<<(n + 255) / 256, 256, 0, stream>>>(fc2_w, w2, n);
        n = NCz * Dz;         f2b_k<<<(n + 255) / 256, 256, 0, stream>>>(head_w, wh, n);
    }

    patch_embed_k<<<BS, 256, 0, stream>>>(x, conv_w, conv_b, cls_tok, pos_emb, tok);

    dim3 blk(256);
    const int MT = (BS + BMt - 1) / BMt;   // 121
    for (int l = 0; l < Lz; ++l) {
        ln_k<<<(BS + 3) / 4, blk, 0, stream>>>(tok, xln, ln1_s + l * Dz, ln1_b + l * Dz, BS);
        mfma_gemm_k<1><<<dim3((3 * Dz + BNt - 1) / BNt, MT), blk, 0, stream>>>(
            xln, wq + (size_t)l * 3 * Dz * Dz, q_bias + l * Dz, v_bias + l * Dz,
            nullptr, qkvb, BS, 3 * Dz, Dz);
        attn_mfma_k<<<Bz * Hz, blk, 0, stream>>>(qkvb, rpb + (size_t)l * NRDz * Hz, xln);
        mfma_gemm_k<2><<<dim3((Dz + BNt - 1) / BNt, MT), blk, 0, stream>>>(
            xln, wp + (size_t)l * Dz * Dz, proj_b + l * Dz, nullptr,
            tok, tok, BS, Dz, Dz);
        ln_k<<<(BS + 3) / 4, blk, 0, stream>>>(tok, xln, ln2_s + l * Dz, ln2_b + l * Dz, BS);
        mfma_gemm_k<3><<<dim3((FFz + BNt - 1) / BNt, MT), blk, 0, stream>>>(
            xln, w1 + (size_t)l * FFz * Dz, fc1_b + l * FFz, nullptr,
            nullptr, mid, BS, FFz, Dz);
        mfma_gemm_k<2><<<dim3((Dz + BNt - 1) / BNt, MT), blk, 0, stream>>>(
            mid, w2 + (size_t)l * Dz * FFz, fc2_b + l * Dz, nullptr,
            tok, tok, BS, Dz, FFz);
    }

    pool_norm_k<<<Bz, blk, 0, stream>>>(tok, fcn_s, fcn_b, pooledb);
    mfma_gemm_k<0><<<dim3((NCz + BNt - 1) / BNt, 1), blk, 0, stream>>>(
        pooledb, wh, head_b, nullptr, nullptr, out, Bz, NCz, Dz);
}

// Round 5
// 2482.680 us; speedup vs baseline: 1.2548x; 1.0913x over previous
//
#include <hip/hip_runtime.h>
#include <math.h>

#define Bz 64
#define Tz 12000
#define Pz 50
#define Dz 200
#define Lz 12
#define Hz 10
#define HDz 20
#define FFz 800
#define Nz 240
#define Sz 241
#define NRDz 482
#define NCz 1000
#define BS (Bz * Sz)          // 15424
#define Mp 15488              // BS padded to 121*128
#define Kp 224                // K=200 padded to 7*32
#define SCALEq 0.22360679774997896f
#define LOG2E 1.4426950408889634f
#define SCALE2f (SCALEq * LOG2E)

typedef __attribute__((ext_vector_type(8))) short bf16x8;
typedef __attribute__((ext_vector_type(4))) float f32x4;

static __device__ __forceinline__ short f2b(float f) {
    unsigned u = __float_as_uint(f);
    unsigned r = (u + 0x7fffu + ((u >> 16) & 1u)) >> 16;
    return (short)r;
}
static __device__ __forceinline__ float b2f(short v) {
    return __uint_as_float(((unsigned)(unsigned short)v) << 16);
}
static __device__ __forceinline__ void gll16(const void* g, void* l) {
    __builtin_amdgcn_global_load_lds((const __attribute__((address_space(1))) unsigned*)g,
                                     (__attribute__((address_space(3))) unsigned*)l, 16, 0, 0);
}

// ---------------- f32 [L][N][K] -> bf16 [L][Npad][Kpad] zero-padded ----------------
__global__ void cvt_pad_k(const float* __restrict__ in, short* __restrict__ out,
                          int N, int K, int Npad, int Kpad, int total) {
    int i = blockIdx.x * 256 + threadIdx.x;
    if (i >= total) return;
    int pk = Npad * Kpad;
    int l = i / pk;
    int r = i - l * pk;
    int n = r / Kpad;
    int k = r - n * Kpad;
    float v = (n < N && k < K) ? in[((size_t)l * N + n) * K + k] : 0.f;
    out[i] = f2b(v);
}

// ---------------- patch embed: tok[b,s,d] f32, stride 200 ----------------
__global__ void patch_embed_k(const float* __restrict__ x, const float* __restrict__ cw,
                              const float* __restrict__ cb, const float* __restrict__ cls,
                              const float* __restrict__ pos, float* __restrict__ tok) {
    int bs = blockIdx.x;
    int b = bs / Sz, s = bs % Sz;
    int d = threadIdx.x;
    __shared__ float xp[Pz];
    if (s == 0) {
        if (d < Dz) tok[(size_t)bs * Dz + d] = cls[d] + pos[d];
        return;
    }
    if (d < Pz) xp[d] = x[(size_t)b * Tz + (s - 1) * Pz + d];
    __syncthreads();
    if (d < Dz) {
        float acc = cb[d];
        const float* w = cw + d * Pz;
        #pragma unroll
        for (int p = 0; p < Pz; ++p) acc += xp[p] * w[p];
        tok[(size_t)bs * Dz + d] = acc + pos[s * Dz + d];
    }
}

// ---------------- layernorm: f32 (ld 200) -> bf16 (ld 224, zero pad cols) ----------------
__global__ void ln_k(const float* __restrict__ in, short* __restrict__ out,
                     const float* __restrict__ sc, const float* __restrict__ bi, int rows) {
    int wave = threadIdx.x >> 6, lane = threadIdx.x & 63;
    int row = blockIdx.x * 4 + wave;
    if (row >= rows) return;
    const float* x = in + (size_t)row * Dz;
    float v[4];
    float sum = 0.f;
    #pragma unroll
    for (int i = 0; i < 4; ++i) {
        int d = lane + 64 * i;
        v[i] = (d < Dz) ? x[d] : 0.f;
        sum += v[i];
    }
    #pragma unroll
    for (int off = 32; off; off >>= 1) sum += __shfl_xor(sum, off);
    float mean = sum * (1.f / Dz);
    float var = 0.f;
    #pragma unroll
    for (int i = 0; i < 4; ++i) {
        int d = lane + 64 * i;
        if (d < Dz) { float t = v[i] - mean; var += t * t; }
    }
    #pragma unroll
    for (int off = 32; off; off >>= 1) var += __shfl_xor(var, off);
    var *= (1.f / Dz);
    float rstd = rsqrtf(var + 1e-6f);
    short* o = out + (size_t)row * Kp;
    #pragma unroll
    for (int i = 0; i < 4; ++i) {
        int d = lane + 64 * i;
        if (d < Dz) o[d] = f2b((v[i] - mean) * rstd * sc[d] + bi[d]);
        else if (d < Kp) o[d] = 0;
    }
}

// ---------------- bias precompute: rpb[l] f32 [482][H] -> bf16 [H][256][256] (k-major, *log2e) ----
__global__ void bias_pre_k(const float* __restrict__ tab, short* __restrict__ bp) {
    int i = blockIdx.x * 256 + threadIdx.x;      // H*65536 total
    int h = i >> 16;
    int kq = i & 65535;
    int k = kq >> 8, q = kq & 255;
    float v;
    if (q > Nz || k > Nz)      v = -1e30f;
    else if (k == 0)           v = (q == 0) ? tab[481 * Hz + h] : tab[480 * Hz + h];
    else if (q == 0)           v = tab[479 * Hz + h];
    else                       v = tab[(q - k + 239) * Hz + h];
    bp[i] = f2b(v * LOG2E);
}

// ---------------- MFMA GEMM v2: out[M,N] = A[M,K] @ W[N,K]^T + epilogue ----------------
// m97 pattern: global_load_lds w16, linear LDS [rows][32] with XOR quad swizzle.
// MODE 0: f32 +bias (head)  MODE 1: bf16 +(q|0|v) bias (qkv)
// MODE 2: f32 +bias+res     MODE 3: bf16 gelu(+bias)
template <int MODE, int BN2>
__global__ __launch_bounds__(256) void gemm2_k(
        const short* __restrict__ A, const short* __restrict__ W,
        const float* __restrict__ bias, const float* __restrict__ bias2,
        const float* __restrict__ res, void* __restrict__ outv,
        int M, int Nreal, int K, int strideA, int ldo) {
    constexpr int NJ = BN2 / 32;        // frags per wave in N
    constexpr int BISS = BN2 / 64;      // B stage issues per wave
    __shared__ short As[128 * 32];
    __shared__ short Bs[BN2 * 32];
    const int t = threadIdx.x;
    const int lane = t & 63, w = t >> 6;
    const int l15 = lane & 15, lg = lane >> 4;
    const int wm = w & 1, wn = w >> 1;
    const int row0 = blockIdx.y * 128, col0 = blockIdx.x * BN2;
    const int xsw = (l15 >> 1) & 3;

    f32x4 acc[4][NJ];
    #pragma unroll
    for (int mi = 0; mi < 4; ++mi)
        #pragma unroll
        for (int nj = 0; nj < NJ; ++nj) {
            f32x4 z = {0.f, 0.f, 0.f, 0.f};
            acc[mi][nj] = z;
        }

    const int nk = K >> 5;
    for (int kt = 0; kt < nk; ++kt) {
        const int k0 = kt * 32;
        #pragma unroll
        for (int i = 0; i < 2; ++i) {
            int c = (w * 2 + i) * 64 + lane;
            int r = c >> 2, q = c & 3;
            const short* gp = A + (size_t)(row0 + r) * strideA + k0 + ((q ^ ((r >> 1) & 3)) * 8);
            gll16(gp, As + (w * 2 + i) * 512);
        }
        #pragma unroll
        for (int i = 0; i < BISS; ++i) {
            int c = (w * BISS + i) * 64 + lane;
            int r = c >> 2, q = c & 3;
            const short* gp = W + (size_t)(col0 + r) * K + k0 + ((q ^ ((r >> 1) & 3)) * 8);
            gll16(gp, Bs + (w * BISS + i) * 512);
        }
        __syncthreads();
        bf16x8 bfr[NJ], afr[4];
        #pragma unroll
        for (int nj = 0; nj < NJ; ++nj)
            bfr[nj] = *(const bf16x8*)(Bs + (wn * (BN2 / 2) + nj * 16 + l15) * 32 + ((lg ^ xsw) * 8));
        #pragma unroll
        for (int mi = 0; mi < 4; ++mi)
            afr[mi] = *(const bf16x8*)(As + (wm * 64 + mi * 16 + l15) * 32 + ((lg ^ xsw) * 8));
        #pragma unroll
        for (int mi = 0; mi < 4; ++mi)
            #pragma unroll
            for (int nj = 0; nj < NJ; ++nj)
                acc[mi][nj] = __builtin_amdgcn_mfma_f32_16x16x32_bf16(afr[mi], bfr[nj], acc[mi][nj], 0, 0, 0);
        __syncthreads();
    }

    #pragma unroll
    for (int mi = 0; mi < 4; ++mi) {
        #pragma unroll
        for (int nj = 0; nj < NJ; ++nj) {
            #pragma unroll
            for (int r = 0; r < 4; ++r) {
                int m = row0 + wm * 64 + mi * 16 + 4 * lg + r;
                int n = col0 + wn * (BN2 / 2) + nj * 16 + l15;
                if (m >= M || n >= Nreal) continue;
                float v = acc[mi][nj][r];
                size_t off = (size_t)m * ldo + n;
                if (MODE == 0) {
                    ((float*)outv)[off] = v + bias[n];
                } else if (MODE == 1) {
                    v += (n < Dz) ? bias[n] : ((n >= 2 * Dz) ? bias2[n - 2 * Dz] : 0.f);
                    ((short*)outv)[off] = f2b(v);
                } else if (MODE == 2) {
                    ((float*)outv)[off] = v + bias[n] + res[off];
                } else {
                    v += bias[n];
                    v = 0.5f * v * (1.f + erff(v * 0.70710678118654752f));
                    ((short*)outv)[off] = f2b(v);
                }
            }
        }
    }
}

// ---------------- MFMA attention v2 ----------------
// qkv bf16 [.][600]; bias bf16 [H][256 k][256 q] (pre *log2e, masked); out bf16 ld 224.
#define PLD 40
__global__ __launch_bounds__(256) void attn_mfma2_k(const short* __restrict__ qkv,
                                                    const short* __restrict__ biasP,
                                                    short* __restrict__ o) {
    const int b = blockIdx.x / Hz, h = blockIdx.x % Hz;
    __shared__ short Ks[256 * 32];          // 16 KB, XOR-quad swizzled
    __shared__ short Vt[32 * 256];          // 16 KB, transposed, XOR swizzled
    __shared__ short Pl[4][64 * PLD];       // 20 KB
    const int t = threadIdx.x;
    const int lane = t & 63, w = t >> 6;
    const int l15 = lane & 15, lg = lane >> 4;
    const size_t brow = (size_t)b * Sz;
    const short* biasPh = biasP + (size_t)h * 65536;

    // zero Vt (pad cols must be 0)
    {
        f32x4 z = {0.f, 0.f, 0.f, 0.f};
        f32x4* vz = (f32x4*)Vt;
        #pragma unroll
        for (int i = 0; i < 4; ++i) vz[t * 4 + i] = z;
    }
    __syncthreads();

    // stage K (swizzled quads, zero-padded) and V^T
    {
        const int s = t;
        short4 kv[5], vv[5];
        short4 z4 = {0, 0, 0, 0};
        if (s < Sz) {
            const short* kp = qkv + (brow + s) * 600 + Dz + h * HDz;
            const short* vp = qkv + (brow + s) * 600 + 2 * Dz + h * HDz;
            #pragma unroll
            for (int c = 0; c < 5; ++c) {
                kv[c] = *(const short4*)(kp + c * 4);
                vv[c] = *(const short4*)(vp + c * 4);
            }
        } else {
            #pragma unroll
            for (int c = 0; c < 5; ++c) { kv[c] = z4; vv[c] = z4; }
        }
        const int sw = (s >> 1) & 3;
        short4 pair0[2] = {kv[0], kv[1]}, pair1[2] = {kv[2], kv[3]},
               pair2[2] = {kv[4], z4}, pair3[2] = {z4, z4};
        *(bf16x8*)(Ks + s * 32 + ((0 ^ sw) * 8)) = *(bf16x8*)pair0;
        *(bf16x8*)(Ks + s * 32 + ((1 ^ sw) * 8)) = *(bf16x8*)pair1;
        *(bf16x8*)(Ks + s * 32 + ((2 ^ sw) * 8)) = *(bf16x8*)pair2;
        *(bf16x8*)(Ks + s * 32 + ((3 ^ sw) * 8)) = *(bf16x8*)pair3;
        if (s < Sz) {
            char* vb = (char*)Vt;
            const short* vs = (const short*)vv;
            #pragma unroll
            for (int d = 0; d < HDz; ++d) {
                int addr = d * 512 + ((s * 2) ^ ((d & 7) << 4));
                *(short*)(vb + addr) = vs[d];
            }
        }
    }

    // Q fragments from global (zero pad d>=20; rows >= Sz read workspace garbage, discarded)
    bf16x8 qfrag[4];
    #pragma unroll
    for (int mi = 0; mi < 4; ++mi) {
        int q = 64 * w + 16 * mi + l15;
        const short* qp = qkv + (brow + q) * 600 + h * HDz + lg * 8;
        short4 lo = {0, 0, 0, 0}, hi = {0, 0, 0, 0};
        if (lg < 3) lo = *(const short4*)qp;
        if (lg < 2) hi = *(const short4*)(qp + 4);
        bf16x8 f;
        f[0] = lo.x; f[1] = lo.y; f[2] = lo.z; f[3] = lo.w;
        f[4] = hi.x; f[5] = hi.y; f[6] = hi.z; f[7] = hi.w;
        qfrag[mi] = f;
    }
    __syncthreads();

    f32x4 O[4][2], mrow[4], lrow[4];
    {
        f32x4 z = {0.f, 0.f, 0.f, 0.f};
        f32x4 mneg = {-1e30f, -1e30f, -1e30f, -1e30f};
        #pragma unroll
        for (int mi = 0; mi < 4; ++mi) {
            O[mi][0] = z; O[mi][1] = z;
            mrow[mi] = mneg; lrow[mi] = z;
        }
    }
    const int xsw = (l15 >> 1) & 3;

    #pragma unroll 1
    for (int kc = 0; kc < 4; ++kc) {
        bf16x8 kf[4];
        #pragma unroll
        for (int nj = 0; nj < 4; ++nj)
            kf[nj] = *(const bf16x8*)(Ks + (kc * 64 + nj * 16 + l15) * 32 + ((lg ^ xsw) * 8));
        f32x4 s[4][4];
        #pragma unroll
        for (int mi = 0; mi < 4; ++mi)
            #pragma unroll
            for (int nj = 0; nj < 4; ++nj) {
                f32x4 z = {0.f, 0.f, 0.f, 0.f};
                s[mi][nj] = __builtin_amdgcn_mfma_f32_16x16x32_bf16(qfrag[mi], kf[nj], z, 0, 0, 0);
            }
        // scale*log2e + precomputed bias (already log2e-domain, masked, specials baked)
        #pragma unroll
        for (int mi = 0; mi < 4; ++mi) {
            int q0 = 64 * w + 16 * mi + 4 * lg;
            #pragma unroll
            for (int nj = 0; nj < 4; ++nj) {
                int kcol = kc * 64 + nj * 16 + l15;
                short4 bp = *(const short4*)(biasPh + (size_t)kcol * 256 + q0);
                s[mi][nj][0] = fmaf(s[mi][nj][0], SCALE2f, b2f(bp.x));
                s[mi][nj][1] = fmaf(s[mi][nj][1], SCALE2f, b2f(bp.y));
                s[mi][nj][2] = fmaf(s[mi][nj][2], SCALE2f, b2f(bp.z));
                s[mi][nj][3] = fmaf(s[mi][nj][3], SCALE2f, b2f(bp.w));
            }
        }
        // online softmax (base-2 domain)
        #pragma unroll
        for (int mi = 0; mi < 4; ++mi) {
            f32x4 pm;
            #pragma unroll
            for (int c = 0; c < 4; ++c)
                pm[c] = fmaxf(fmaxf(s[mi][0][c], s[mi][1][c]), fmaxf(s[mi][2][c], s[mi][3][c]));
            #pragma unroll
            for (int msk = 1; msk <= 8; msk <<= 1)
                #pragma unroll
                for (int c = 0; c < 4; ++c) pm[c] = fmaxf(pm[c], __shfl_xor(pm[c], msk));
            f32x4 mn, sc;
            #pragma unroll
            for (int c = 0; c < 4; ++c) {
                mn[c] = fmaxf(mrow[mi][c], pm[c]);
                sc[c] = exp2f(mrow[mi][c] - mn[c]);
            }
            mrow[mi] = mn;
            f32x4 ls = {0.f, 0.f, 0.f, 0.f};
            #pragma unroll
            for (int nj = 0; nj < 4; ++nj) {
                #pragma unroll
                for (int c = 0; c < 4; ++c) s[mi][nj][c] = exp2f(s[mi][nj][c] - mn[c]);
                ls += s[mi][nj];
            }
            #pragma unroll
            for (int msk = 1; msk <= 8; msk <<= 1)
                #pragma unroll
                for (int c = 0; c < 4; ++c) ls[c] += __shfl_xor(ls[c], msk);
            lrow[mi] = lrow[mi] * sc + ls;
            O[mi][0] *= sc;
            O[mi][1] *= sc;
        }
        // PV via per-wave P tile, two K=32 halves
        #pragma unroll
        for (int kk = 0; kk < 2; ++kk) {
            #pragma unroll
            for (int mi = 0; mi < 4; ++mi)
                #pragma unroll
                for (int njh = 0; njh < 2; ++njh) {
                    int nj = kk * 2 + njh;
                    #pragma unroll
                    for (int r = 0; r < 4; ++r)
                        Pl[w][(mi * 16 + 4 * lg + r) * PLD + njh * 16 + l15] = f2b(s[mi][nj][r]);
                }
            bf16x8 vf[2];
            #pragma unroll
            for (int dj = 0; dj < 2; ++dj) {
                int d = dj * 16 + l15;
                int cb = (kc * 128 + kk * 64 + lg * 16) ^ ((l15 & 7) << 4);
                vf[dj] = *(const bf16x8*)((const char*)Vt + d * 512 + cb);
            }
            #pragma unroll
            for (int mi = 0; mi < 4; ++mi) {
                bf16x8 af = *(const bf16x8*)(Pl[w] + (mi * 16 + l15) * PLD + lg * 8);
                O[mi][0] = __builtin_amdgcn_mfma_f32_16x16x32_bf16(af, vf[0], O[mi][0], 0, 0, 0);
                O[mi][1] = __builtin_amdgcn_mfma_f32_16x16x32_bf16(af, vf[1], O[mi][1], 0, 0, 0);
            }
        }
    }

    #pragma unroll
    for (int mi = 0; mi < 4; ++mi) {
        f32x4 inv;
        #pragma unroll
        for (int c = 0; c < 4; ++c) inv[c] = 1.f / lrow[mi][c];
        #pragma unroll
        for (int dj = 0; dj < 2; ++dj) {
            int d = dj * 16 + l15;
            if (d >= HDz) continue;
            #pragma unroll
            for (int r = 0; r < 4; ++r) {
                int q = 64 * w + 16 * mi + 4 * lg + r;
                if (q < Sz)
                    o[(brow + q) * Kp + h * HDz + d] = f2b(O[mi][dj][r] * inv[r]);
            }
        }
    }
}

// ---------------- pool + fc_norm -> bf16 pooled [128][224] ----------------
__global__ void pool_norm_k(const float* __restrict__ tok, const float* __restrict__ sc,
                            const float* __restrict__ bi, short* __restrict__ pooled) {
    int b = blockIdx.x;
    int t = threadIdx.x;
    float val = 0.f;
    if (t < Dz) {
        const float* base = tok + ((size_t)b * Sz + 1) * Dz + t;
        float s = 0.f;
        for (int si = 0; si < Nz; ++si) s += base[(size_t)si * Dz];
        val = s * (1.f / Nz);
    }
    __shared__ float red[8];
    float sum = val, sq = val * val;
    #pragma unroll
    for (int off = 32; off; off >>= 1) { sum += __shfl_xor(sum, off); sq += __shfl_xor(sq, off); }
    int wave = t >> 6, lane = t & 63;
    if (lane == 0) { red[wave] = sum; red[4 + wave] = sq; }
    __syncthreads();
    sum = red[0] + red[1] + red[2] + red[3];
    sq = red[4] + red[5] + red[6] + red[7];
    float mean = sum * (1.f / Dz);
    float var = sq * (1.f / Dz) - mean * mean;
    float rstd = rsqrtf(var + 1e-6f);
    if (t < Dz) pooled[(size_t)b * Kp + t] = f2b((val - mean) * rstd * sc[t] + bi[t]);
    else if (t < Kp) pooled[(size_t)b * Kp + t] = 0;
}

extern "C" void kernel_launch(void* const* d_in, const int* in_sizes, int n_in,
                              void* d_out, int out_size, void* d_ws, size_t ws_size,
                              hipStream_t stream) {
    const float* x        = (const float*)d_in[0];
    const float* conv_w   = (const float*)d_in[1];
    const float* conv_b   = (const float*)d_in[2];
    const float* cls_tok  = (const float*)d_in[3];
    const float* pos_emb  = (const float*)d_in[4];
    const float* ln1_s    = (const float*)d_in[5];
    const float* ln1_b    = (const float*)d_in[6];
    const float* qkv_w    = (const float*)d_in[7];
    const float* q_bias   = (const float*)d_in[8];
    const float* v_bias   = (const float*)d_in[9];
    const float* rpb      = (const float*)d_in[10];
    const float* proj_w   = (const float*)d_in[11];
    const float* proj_b   = (const float*)d_in[12];
    const float* ln2_s    = (const float*)d_in[13];
    const float* ln2_b    = (const float*)d_in[14];
    const float* fc1_w    = (const float*)d_in[15];
    const float* fc1_b    = (const float*)d_in[16];
    const float* fc2_w    = (const float*)d_in[17];
    const float* fc2_b    = (const float*)d_in[18];
    const float* fcn_s    = (const float*)d_in[19];
    const float* fcn_b    = (const float*)d_in[20];
    const float* head_w   = (const float*)d_in[21];
    const float* head_b   = (const float*)d_in[22];
    float* out = (float*)d_out;

    char* ws = (char*)d_ws;
    float* tok  = (float*)ws;  ws += (size_t)BS * Dz * 4;        // 12.34 MB, ld 200
    short* xln  = (short*)ws;  ws += (size_t)Mp * Kp * 2;        // 6.94 MB, ld 224
    short* big  = (short*)ws;  ws += (size_t)Mp * FFz * 2;       // 24.78 MB (qkvb ld600 / mid ld800)
    short* wq = (short*)ws;    ws += (size_t)Lz * 640 * Kp * 2;
    short* wp = (short*)ws;    ws += (size_t)Lz * 256 * Kp * 2;
    short* w1 = (short*)ws;    ws += (size_t)Lz * 896 * Kp * 2;
    short* w2 = (short*)ws;    ws += (size_t)Lz * 256 * FFz * 2;
    short* wh = (short*)ws;    ws += (size_t)1024 * Kp * 2;
    short* biasPbuf = (short*)ws; ws += (size_t)Hz * 256 * 256 * 2;
    short* pooledb = (short*)ws;
    short* qkvb = big;
    short* mid  = big;

    // weight conversions (padded)
    {
        int n;
        n = Lz * 640 * Kp;  cvt_pad_k<<<(n + 255) / 256, 256, 0, stream>>>(qkv_w, wq, 600, 200, 640, Kp, n);
        n = Lz * 256 * Kp;  cvt_pad_k<<<(n + 255) / 256, 256, 0, stream>>>(proj_w, wp, 200, 200, 256, Kp, n);
        n = Lz * 896 * Kp;  cvt_pad_k<<<(n + 255) / 256, 256, 0, stream>>>(fc1_w, w1, 800, 200, 896, Kp, n);
        n = Lz * 256 * FFz; cvt_pad_k<<<(n + 255) / 256, 256, 0, stream>>>(fc2_w, w2, 200, 800, 256, FFz, n);
        n = 1024 * Kp;      cvt_pad_k<<<(n + 255) / 256, 256, 0, stream>>>(head_w, wh, 1000, 200, 1024, Kp, n);
    }

    patch_embed_k<<<BS, 256, 0, stream>>>(x, conv_w, conv_b, cls_tok, pos_emb, tok);

    dim3 blk(256);
    for (int l = 0; l < Lz; ++l) {
        bias_pre_k<<<(Hz * 65536) / 256, blk, 0, stream>>>(rpb + (size_t)l * NRDz * Hz, biasPbuf);
        ln_k<<<(BS + 3) / 4, blk, 0, stream>>>(tok, xln, ln1_s + l * Dz, ln1_b + l * Dz, BS);
        gemm2_k<1, 128><<<dim3(5, 121), blk, 0, stream>>>(
            xln, wq + (size_t)l * 640 * Kp, q_bias + l * Dz, v_bias + l * Dz,
            nullptr, qkvb, BS, 600, Kp, Kp, 600);
        attn_mfma2_k<<<Bz * Hz, blk, 0, stream>>>(qkvb, biasPbuf, xln);
        gemm2_k<2, 64><<<dim3(4, 121), blk, 0, stream>>>(
            xln, wp + (size_t)l * 256 * Kp, proj_b + l * Dz, nullptr,
            tok, tok, BS, Dz, Kp, Kp, Dz);
        ln_k<<<(BS + 3) / 4, blk, 0, stream>>>(tok, xln, ln2_s + l * Dz, ln2_b + l * Dz, BS);
        gemm2_k<3, 128><<<dim3(7, 121), blk, 0, stream>>>(
            xln, w1 + (size_t)l * 896 * Kp, fc1_b + l * FFz, nullptr,
            nullptr, mid, BS, FFz, Kp, Kp, FFz);
        gemm2_k<2, 64><<<dim3(4, 121), blk, 0, stream>>>(
            mid, w2 + (size_t)l * 256 * FFz, fc2_b + l * Dz, nullptr,
            tok, tok, BS, Dz, FFz, FFz, Dz);
    }

    pool_norm_k<<<Bz, blk, 0, stream>>>(tok, fcn_s, fcn_b, pooledb);
    gemm2_k<0, 128><<<dim3(8, 1), blk, 0, stream>>>(
        pooledb, wh, head_b, nullptr, nullptr, out, Bz, NCz, Kp, Kp, NCz);
}

// Round 7
// 2218.062 us; speedup vs baseline: 1.4045x; 1.1193x over previous
//
#include <hip/hip_runtime.h>
#include <math.h>

#define Bz 64
#define Tz 12000
#define Pz 50
#define Dz 200
#define Lz 12
#define Hz 10
#define HDz 20
#define FFz 800
#define Nz 240
#define Sz 241
#define Sp 256                // padded seq stride
#define NRDz 482
#define NCz 1000
#define BS (Bz * Sz)          // 15424 valid rows
#define Mp (Bz * Sp)          // 16384 padded rows
#define Kp 224                // K=200 padded to 7*32
#define SCALEq 0.22360679774997896f
#define LOG2E 1.4426950408889634f
#define SCALE2f (SCALEq * LOG2E)

typedef __attribute__((ext_vector_type(8))) short bf16x8;
typedef __attribute__((ext_vector_type(4))) float f32x4;

static __device__ __forceinline__ short f2b(float f) {
    unsigned u = __float_as_uint(f);
    unsigned r = (u + 0x7fffu + ((u >> 16) & 1u)) >> 16;
    return (short)r;
}
static __device__ __forceinline__ float b2f(short v) {
    return __uint_as_float(((unsigned)(unsigned short)v) << 16);
}
static __device__ __forceinline__ void gll16(const void* g, void* l) {
    __builtin_amdgcn_global_load_lds((const __attribute__((address_space(1))) unsigned*)g,
                                     (__attribute__((address_space(3))) unsigned*)l, 16, 0, 0);
}

// ---------------- f32 [L][N][K] -> bf16 [L][Npad][Kpad] zero-padded ----------------
__global__ void cvt_pad_k(const float* __restrict__ in, short* __restrict__ out,
                          int N, int K, int Npad, int Kpad, int total) {
    int i = blockIdx.x * 256 + threadIdx.x;
    if (i >= total) return;
    int pk = Npad * Kpad;
    int l = i / pk;
    int r = i - l * pk;
    int n = r / Kpad;
    int k = r - n * Kpad;
    float v = (n < N && k < K) ? in[((size_t)l * N + n) * K + k] : 0.f;
    out[i] = f2b(v);
}

// ---------------- patch embed -> tok padded rows ----------------
__global__ void patch_embed_k(const float* __restrict__ x, const float* __restrict__ cw,
                              const float* __restrict__ cb, const float* __restrict__ cls,
                              const float* __restrict__ pos, float* __restrict__ tok) {
    int bs = blockIdx.x;              // 0..BS-1 dense
    int b = bs / Sz, s = bs % Sz;
    int d = threadIdx.x;
    size_t row = (size_t)b * Sp + s;
    __shared__ float xp[Pz];
    if (s == 0) {
        if (d < Dz) tok[row * Dz + d] = cls[d] + pos[d];
        return;
    }
    if (d < Pz) xp[d] = x[(size_t)b * Tz + (s - 1) * Pz + d];
    __syncthreads();
    if (d < Dz) {
        float acc = cb[d];
        const float* w = cw + d * Pz;
        #pragma unroll
        for (int p = 0; p < Pz; ++p) acc += xp[p] * w[p];
        tok[row * Dz + d] = acc + pos[s * Dz + d];
    }
}

// ---------------- layernorm: f32 (padded rows, ld 200) -> bf16 (ld 224) ----------------
__global__ void ln_k(const float* __restrict__ in, short* __restrict__ out,
                     const float* __restrict__ sc, const float* __restrict__ bi) {
    int wave = threadIdx.x >> 6, lane = threadIdx.x & 63;
    int row = blockIdx.x * 4 + wave;
    if ((row & 255) >= Sz) return;      // pad row
    const float* x = in + (size_t)row * Dz;
    float v[4];
    float sum = 0.f;
    #pragma unroll
    for (int i = 0; i < 4; ++i) {
        int d = lane + 64 * i;
        v[i] = (d < Dz) ? x[d] : 0.f;
        sum += v[i];
    }
    #pragma unroll
    for (int off = 32; off; off >>= 1) sum += __shfl_xor(sum, off);
    float mean = sum * (1.f / Dz);
    float var = 0.f;
    #pragma unroll
    for (int i = 0; i < 4; ++i) {
        int d = lane + 64 * i;
        if (d < Dz) { float t = v[i] - mean; var += t * t; }
    }
    #pragma unroll
    for (int off = 32; off; off >>= 1) var += __shfl_xor(var, off);
    var *= (1.f / Dz);
    float rstd = rsqrtf(var + 1e-6f);
    short* o = out + (size_t)row * Kp;
    #pragma unroll
    for (int i = 0; i < 4; ++i) {
        int d = lane + 64 * i;
        if (d < Dz) o[d] = f2b((v[i] - mean) * rstd * sc[d] + bi[d]);
        else if (d < Kp) o[d] = 0;
    }
}

// ---------------- bias precompute in per-lane fragment order ----------------
// idx4 = lane + 64*mi + 128*w + 512*qb + 1024*nj + 4096*kc + 16384*h; short4 each.
__global__ void bias_pre3_k(const float* __restrict__ tab, short* __restrict__ bp) {
    int tid = blockIdx.x * 256 + threadIdx.x;      // 163840 total
    int lane = tid & 63;
    int mi = (tid >> 6) & 1;
    int w  = (tid >> 7) & 3;
    int qb = (tid >> 9) & 1;
    int nj = (tid >> 10) & 3;
    int kc = (tid >> 12) & 3;
    int h  = tid >> 14;
    int q0 = qb * 128 + w * 32 + mi * 16 + 4 * (lane >> 4);
    int k  = kc * 64 + nj * 16 + (lane & 15);
    short4 o;
    #pragma unroll
    for (int r = 0; r < 4; ++r) {
        int q = q0 + r;
        float v;
        if (q > Nz || k > Nz) v = -1e30f;
        else if (k == 0)      v = (q == 0) ? tab[481 * Hz + h] : tab[480 * Hz + h];
        else if (q == 0)      v = tab[479 * Hz + h];
        else                  v = tab[(q - k + 239) * Hz + h];
        ((short*)&o)[r] = f2b(v * LOG2E);
    }
    *(short4*)(bp + (size_t)tid * 4) = o;
}

// ---------------- MFMA GEMM: out[M,N] = A[M,K] @ W[N,K]^T + epilogue ----------------
// MODE 0: f32 +bias (head)   MODE 1: qkv -> Qb/Kb/Vtb (pre-scaled Q, swizzled K/Vt)
// MODE 2: f32 +bias+res      MODE 3: bf16 gelu(+bias)
template <int MODE, int BN2>
__global__ __launch_bounds__(256) void gemm2_k(
        const short* __restrict__ A, const short* __restrict__ W,
        const float* __restrict__ bias, const float* __restrict__ bias2,
        const float* __restrict__ res, void* __restrict__ outv,
        short* __restrict__ qo, short* __restrict__ ko, short* __restrict__ vo,
        int M, int Nreal, int K, int strideA, int ldo) {
    constexpr int NJ = BN2 / 32;
    constexpr int BISS = BN2 / 64;
    __shared__ short As[128 * 32];
    __shared__ short Bs[BN2 * 32];
    const int t = threadIdx.x;
    const int lane = t & 63, w = t >> 6;
    const int l15 = lane & 15, lg = lane >> 4;
    const int wm = w & 1, wn = w >> 1;
    const int row0 = blockIdx.y * 128, col0 = blockIdx.x * BN2;
    const int xsw = (l15 >> 1) & 3;

    f32x4 acc[4][NJ];
    #pragma unroll
    for (int mi = 0; mi < 4; ++mi)
        #pragma unroll
        for (int nj = 0; nj < NJ; ++nj) {
            f32x4 z = {0.f, 0.f, 0.f, 0.f};
            acc[mi][nj] = z;
        }

    const int nk = K >> 5;
    for (int kt = 0; kt < nk; ++kt) {
        const int k0 = kt * 32;
        #pragma unroll
        for (int i = 0; i < 2; ++i) {
            int c = (w * 2 + i) * 64 + lane;
            int r = c >> 2, q = c & 3;
            const short* gp = A + (size_t)(row0 + r) * strideA + k0 + ((q ^ ((r >> 1) & 3)) * 8);
            gll16(gp, As + (w * 2 + i) * 512);
        }
        #pragma unroll
        for (int i = 0; i < BISS; ++i) {
            int c = (w * BISS + i) * 64 + lane;
            int r = c >> 2, q = c & 3;
            const short* gp = W + (size_t)(col0 + r) * K + k0 + ((q ^ ((r >> 1) & 3)) * 8);
            gll16(gp, Bs + (w * BISS + i) * 512);
        }
        __syncthreads();
        bf16x8 bfr[NJ], afr[4];
        #pragma unroll
        for (int nj = 0; nj < NJ; ++nj)
            bfr[nj] = *(const bf16x8*)(Bs + (wn * (BN2 / 2) + nj * 16 + l15) * 32 + ((lg ^ xsw) * 8));
        #pragma unroll
        for (int mi = 0; mi < 4; ++mi)
            afr[mi] = *(const bf16x8*)(As + (wm * 64 + mi * 16 + l15) * 32 + ((lg ^ xsw) * 8));
        #pragma unroll
        for (int mi = 0; mi < 4; ++mi)
            #pragma unroll
            for (int nj = 0; nj < NJ; ++nj)
                acc[mi][nj] = __builtin_amdgcn_mfma_f32_16x16x32_bf16(afr[mi], bfr[nj], acc[mi][nj], 0, 0, 0);
        __syncthreads();
    }

    #pragma unroll
    for (int mi = 0; mi < 4; ++mi) {
        #pragma unroll
        for (int nj = 0; nj < NJ; ++nj) {
            int n = col0 + wn * (BN2 / 2) + nj * 16 + l15;
            if (n >= Nreal) continue;
            if (MODE == 1) {
                // padded rows: b = m0>>8, s0 = m0&255 (s0 % 4 == 0 guaranteed)
                int which = n >= 400 ? 2 : (n >= 200 ? 1 : 0);
                int hd = n - which * 200;
                int h = hd / 20, d = hd - h * 20;
                int m0 = row0 + wm * 64 + mi * 16 + 4 * lg;
                int b = m0 >> 8, s0 = m0 & 255;
                size_t base = (size_t)(b * Hz + h) * 8192;
                if (which == 2) {
                    short4 o4;
                    float vb = bias2[hd];
                    #pragma unroll
                    for (int r = 0; r < 4; ++r)
                        ((short*)&o4)[r] = f2b(acc[mi][nj][r] + vb);
                    *(short4*)(vo + base + d * 256 + (s0 ^ ((d & 7) << 3))) = o4;
                } else if (which == 0) {
                    float qb = bias[hd];
                    #pragma unroll
                    for (int r = 0; r < 4; ++r)
                        qo[base + (s0 + r) * 32 + d] = f2b((acc[mi][nj][r] + qb) * SCALE2f);
                } else {
                    #pragma unroll
                    for (int r = 0; r < 4; ++r) {
                        int s = s0 + r;
                        ko[base + s * 32 + (((d >> 3) ^ ((s >> 1) & 3)) * 8) + (d & 7)] = f2b(acc[mi][nj][r]);
                    }
                }
            } else {
                #pragma unroll
                for (int r = 0; r < 4; ++r) {
                    int m = row0 + wm * 64 + mi * 16 + 4 * lg + r;
                    if (m >= M) continue;
                    float v = acc[mi][nj][r];
                    size_t off = (size_t)m * ldo + n;
                    if (MODE == 0) {
                        ((float*)outv)[off] = v + bias[n];
                    } else if (MODE == 2) {
                        ((float*)outv)[off] = v + bias[n] + res[off];
                    } else {
                        v += bias[n];
                        v = 0.5f * v * (1.f + erff(v * 0.70710678118654752f));
                        ((short*)outv)[off] = f2b(v);
                    }
                }
            }
        }
    }
}

// ---------------- MFMA attention v3: separated pre-swizzled inputs ----------------
// 1280 blocks: (bh, q-half). LDS: Ks 16KB + Vt 16KB + Pl 10KB = 42.25KB.
#define PLD 40
__global__ __launch_bounds__(256) void attn3_k(const short* __restrict__ Qb,
                                               const short* __restrict__ Kb,
                                               const short* __restrict__ Vtb,
                                               const short* __restrict__ biasC,
                                               short* __restrict__ o) {
    const int blk = blockIdx.x;
    const int qb = blk & 1;
    const int bh = blk >> 1;
    const int b = bh / Hz, h = bh - b * Hz;
    __shared__ short Ks[8192];
    __shared__ short Vt[8192];
    __shared__ short Pl[4][32 * PLD];
    const int t = threadIdx.x;
    const int lane = t & 63, w = t >> 6;
    const int l15 = lane & 15, lg = lane >> 4;

    // stage K and V^T: linear DMA (source layouts pre-swizzled)
    const short* kbh = Kb + (size_t)bh * 8192;
    const short* vbh = Vtb + (size_t)bh * 8192;
    #pragma unroll
    for (int i = 0; i < 4; ++i) {
        int j = w * 4 + i;
        gll16(kbh + (size_t)(j * 64 + lane) * 8, Ks + j * 512);
        gll16(vbh + (size_t)(j * 64 + lane) * 8, Vt + j * 512);
    }
    // Q fragments (coalesced; pre-scaled by SCALEq*log2e)
    bf16x8 qfrag[2];
    const short* qbh = Qb + (size_t)bh * 8192;
    #pragma unroll
    for (int mi = 0; mi < 2; ++mi) {
        int qrow = qb * 128 + w * 32 + mi * 16 + l15;
        qfrag[mi] = *(const bf16x8*)(qbh + qrow * 32 + lg * 8);
    }
    const short* bpp = biasC + 4 * (size_t)(lane + 128 * w + 512 * qb + 16384 * h);
    __syncthreads();

    f32x4 O[2][2], mrow[2], lrow[2];
    {
        f32x4 z = {0.f, 0.f, 0.f, 0.f};
        f32x4 mneg = {-1e30f, -1e30f, -1e30f, -1e30f};
        #pragma unroll
        for (int mi = 0; mi < 2; ++mi) {
            O[mi][0] = z; O[mi][1] = z;
            mrow[mi] = mneg; lrow[mi] = z;
        }
    }
    const int xsw = (l15 >> 1) & 3;

    #pragma unroll 1
    for (int kc = 0; kc < 4; ++kc) {
        bf16x8 kf[4];
        #pragma unroll
        for (int nj = 0; nj < 4; ++nj)
            kf[nj] = *(const bf16x8*)(Ks + (kc * 64 + nj * 16 + l15) * 32 + ((lg ^ xsw) * 8));
        f32x4 s[2][4];
        #pragma unroll
        for (int mi = 0; mi < 2; ++mi)
            #pragma unroll
            for (int nj = 0; nj < 4; ++nj) {
                f32x4 z = {0.f, 0.f, 0.f, 0.f};
                s[mi][nj] = __builtin_amdgcn_mfma_f32_16x16x32_bf16(qfrag[mi], kf[nj], z, 0, 0, 0);
            }
        const short* bkc = bpp + kc * 16384;
        #pragma unroll
        for (int mi = 0; mi < 2; ++mi)
            #pragma unroll
            for (int nj = 0; nj < 4; ++nj) {
                short4 bp4 = *(const short4*)(bkc + nj * 4096 + mi * 256);
                s[mi][nj][0] += b2f(bp4.x);
                s[mi][nj][1] += b2f(bp4.y);
                s[mi][nj][2] += b2f(bp4.z);
                s[mi][nj][3] += b2f(bp4.w);
            }
        // online softmax (base-2)
        #pragma unroll
        for (int mi = 0; mi < 2; ++mi) {
            f32x4 pm;
            #pragma unroll
            for (int c = 0; c < 4; ++c)
                pm[c] = fmaxf(fmaxf(s[mi][0][c], s[mi][1][c]), fmaxf(s[mi][2][c], s[mi][3][c]));
            #pragma unroll
            for (int msk = 1; msk <= 8; msk <<= 1)
                #pragma unroll
                for (int c = 0; c < 4; ++c) pm[c] = fmaxf(pm[c], __shfl_xor(pm[c], msk));
            f32x4 mn, sc;
            #pragma unroll
            for (int c = 0; c < 4; ++c) {
                mn[c] = fmaxf(mrow[mi][c], pm[c]);
                sc[c] = exp2f(mrow[mi][c] - mn[c]);
            }
            mrow[mi] = mn;
            f32x4 ls = {0.f, 0.f, 0.f, 0.f};
            #pragma unroll
            for (int nj = 0; nj < 4; ++nj) {
                #pragma unroll
                for (int c = 0; c < 4; ++c) s[mi][nj][c] = exp2f(s[mi][nj][c] - mn[c]);
                ls += s[mi][nj];
            }
            #pragma unroll
            for (int msk = 1; msk <= 8; msk <<= 1)
                #pragma unroll
                for (int c = 0; c < 4; ++c) ls[c] += __shfl_xor(ls[c], msk);
            lrow[mi] = lrow[mi] * sc + ls;
            O[mi][0] *= sc;
            O[mi][1] *= sc;
        }
        // PV via per-wave P tile, two K=32 halves
        #pragma unroll
        for (int kk = 0; kk < 2; ++kk) {
            #pragma unroll
            for (int mi = 0; mi < 2; ++mi)
                #pragma unroll
                for (int njh = 0; njh < 2; ++njh) {
                    int nj = kk * 2 + njh;
                    #pragma unroll
                    for (int r = 0; r < 4; ++r)
                        Pl[w][(mi * 16 + 4 * lg + r) * PLD + njh * 16 + l15] = f2b(s[mi][nj][r]);
                }
            bf16x8 vf[2];
            #pragma unroll
            for (int dj = 0; dj < 2; ++dj) {
                int d = dj * 16 + l15;
                int cb = (kc * 128 + kk * 64 + lg * 16) ^ ((l15 & 7) << 4);
                vf[dj] = *(const bf16x8*)((const char*)Vt + d * 512 + cb);
            }
            #pragma unroll
            for (int mi = 0; mi < 2; ++mi) {
                bf16x8 af = *(const bf16x8*)(Pl[w] + (mi * 16 + l15) * PLD + lg * 8);
                O[mi][0] = __builtin_amdgcn_mfma_f32_16x16x32_bf16(af, vf[0], O[mi][0], 0, 0, 0);
                O[mi][1] = __builtin_amdgcn_mfma_f32_16x16x32_bf16(af, vf[1], O[mi][1], 0, 0, 0);
            }
        }
    }

    #pragma unroll
    for (int mi = 0; mi < 2; ++mi) {
        f32x4 inv;
        #pragma unroll
        for (int c = 0; c < 4; ++c) inv[c] = 1.f / lrow[mi][c];
        #pragma unroll
        for (int dj = 0; dj < 2; ++dj) {
            int d = dj * 16 + l15;
            if (d >= HDz) continue;
            #pragma unroll
            for (int r = 0; r < 4; ++r) {
                int q = qb * 128 + w * 32 + mi * 16 + 4 * lg + r;
                if (q < Sz)
                    o[((size_t)b * Sp + q) * Kp + h * HDz + d] = f2b(O[mi][dj][r] * inv[r]);
            }
        }
    }
}

// ---------------- pool + fc_norm -> bf16 pooled [128][224] ----------------
__global__ void pool_norm_k(const float* __restrict__ tok, const float* __restrict__ sc,
                            const float* __restrict__ bi, short* __restrict__ pooled) {
    int b = blockIdx.x;
    int t = threadIdx.x;
    float val = 0.f;
    if (t < Dz) {
        const float* base = tok + ((size_t)b * Sp + 1) * Dz + t;
        float s = 0.f;
        for (int si = 0; si < Nz; ++si) s += base[(size_t)si * Dz];
        val = s * (1.f / Nz);
    }
    __shared__ float red[8];
    float sum = val, sq = val * val;
    #pragma unroll
    for (int off = 32; off; off >>= 1) { sum += __shfl_xor(sum, off); sq += __shfl_xor(sq, off); }
    int wave = t >> 6, lane = t & 63;
    if (lane == 0) { red[wave] = sum; red[4 + wave] = sq; }
    __syncthreads();
    sum = red[0] + red[1] + red[2] + red[3];
    sq = red[4] + red[5] + red[6] + red[7];
    float mean = sum * (1.f / Dz);
    float var = sq * (1.f / Dz) - mean * mean;
    float rstd = rsqrtf(var + 1e-6f);
    if (t < Dz) pooled[(size_t)b * Kp + t] = f2b((val - mean) * rstd * sc[t] + bi[t]);
    else if (t < Kp) pooled[(size_t)b * Kp + t] = 0;
}

extern "C" void kernel_launch(void* const* d_in, const int* in_sizes, int n_in,
                              void* d_out, int out_size, void* d_ws, size_t ws_size,
                              hipStream_t stream) {
    const float* x        = (const float*)d_in[0];
    const float* conv_w   = (const float*)d_in[1];
    const float* conv_b   = (const float*)d_in[2];
    const float* cls_tok  = (const float*)d_in[3];
    const float* pos_emb  = (const float*)d_in[4];
    const float* ln1_s    = (const float*)d_in[5];
    const float* ln1_b    = (const float*)d_in[6];
    const float* qkv_w    = (const float*)d_in[7];
    const float* q_bias   = (const float*)d_in[8];
    const float* v_bias   = (const float*)d_in[9];
    const float* rpb      = (const float*)d_in[10];
    const float* proj_w   = (const float*)d_in[11];
    const float* proj_b   = (const float*)d_in[12];
    const float* ln2_s    = (const float*)d_in[13];
    const float* ln2_b    = (const float*)d_in[14];
    const float* fc1_w    = (const float*)d_in[15];
    const float* fc1_b    = (const float*)d_in[16];
    const float* fc2_w    = (const float*)d_in[17];
    const float* fc2_b    = (const float*)d_in[18];
    const float* fcn_s    = (const float*)d_in[19];
    const float* fcn_b    = (const float*)d_in[20];
    const float* head_w   = (const float*)d_in[21];
    const float* head_b   = (const float*)d_in[22];
    float* out = (float*)d_out;

    char* ws = (char*)d_ws;
    float* tok  = (float*)ws;  ws += (size_t)Mp * Dz * 4;        // 13.11 MB
    short* xln  = (short*)ws;  ws += (size_t)Mp * Kp * 2;        // 7.34 MB
    short* mid  = (short*)ws;  ws += (size_t)Mp * FFz * 2;       // 26.21 MB
    short* Qb   = (short*)ws;  ws += (size_t)640 * 8192 * 2;     // 10.49 MB
    short* Kb   = (short*)ws;  ws += (size_t)640 * 8192 * 2;
    short* Vtb  = (short*)ws;  ws += (size_t)640 * 8192 * 2;
    short* wq = (short*)ws;    ws += (size_t)Lz * 640 * Kp * 2;
    short* wp = (short*)ws;    ws += (size_t)Lz * 256 * Kp * 2;
    short* w1 = (short*)ws;    ws += (size_t)Lz * 896 * Kp * 2;
    short* w2 = (short*)ws;    ws += (size_t)Lz * 256 * FFz * 2;
    short* wh = (short*)ws;    ws += (size_t)1024 * Kp * 2;
    short* biasC = (short*)ws; ws += (size_t)163840 * 4 * 2;     // 1.31 MB
    short* pooledb = (short*)ws;                                  // 128*224

    // zero xln (pad rows must stay 0) and Q/K/Vt pad regions — once per launch
    hipMemsetAsync(xln, 0, (size_t)Mp * Kp * 2, stream);
    hipMemsetAsync(Qb, 0, (size_t)640 * 8192 * 2 * 3, stream);

    {
        int n;
        n = Lz * 640 * Kp;  cvt_pad_k<<<(n + 255) / 256, 256, 0, stream>>>(qkv_w, wq, 600, 200, 640, Kp, n);
        n = Lz * 256 * Kp;  cvt_pad_k<<<(n + 255) / 256, 256, 0, stream>>>(proj_w, wp, 200, 200, 256, Kp, n);
        n = Lz * 896 * Kp;  cvt_pad_k<<<(n + 255) / 256, 256, 0, stream>>>(fc1_w, w1, 800, 200, 896, Kp, n);
        n = Lz * 256 * FFz; cvt_pad_k<<<(n + 255) / 256, 256, 0, stream>>>(fc2_w, w2, 200, 800, 256, FFz, n);
        n = 1024 * Kp;      cvt_pad_k<<<(n + 255) / 256, 256, 0, stream>>>(head_w, wh, 1000, 200, 1024, Kp, n);
    }

    patch_embed_k<<<BS, 256, 0, stream>>>(x, conv_w, conv_b, cls_tok, pos_emb, tok);

    dim3 blk(256);
    for (int l = 0; l < Lz; ++l) {
        bias_pre3_k<<<640, blk, 0, stream>>>(rpb + (size_t)l * NRDz * Hz, biasC);
        ln_k<<<Mp / 4, blk, 0, stream>>>(tok, xln, ln1_s + l * Dz, ln1_b + l * Dz);
        gemm2_k<1, 128><<<dim3(5, Mp / 128), blk, 0, stream>>>(
            xln, wq + (size_t)l * 640 * Kp, q_bias + l * Dz, v_bias + l * Dz,
            nullptr, nullptr, Qb, Kb, Vtb, Mp, 600, Kp, Kp, 0);
        attn3_k<<<1280, blk, 0, stream>>>(Qb, Kb, Vtb, biasC, xln);
        gemm2_k<2, 64><<<dim3(4, Mp / 128), blk, 0, stream>>>(
            xln, wp + (size_t)l * 256 * Kp, proj_b + l * Dz, nullptr,
            tok, tok, nullptr, nullptr, nullptr, Mp, Dz, Kp, Kp, Dz);
        ln_k<<<Mp / 4, blk, 0, stream>>>(tok, xln, ln2_s + l * Dz, ln2_b + l * Dz);
        gemm2_k<3, 128><<<dim3(7, Mp / 128), blk, 0, stream>>>(
            xln, w1 + (size_t)l * 896 * Kp, fc1_b + l * FFz, nullptr,
            nullptr, mid, nullptr, nullptr, nullptr, Mp, FFz, Kp, Kp, FFz);
        gemm2_k<2, 64><<<dim3(4, Mp / 128), blk, 0, stream>>>(
            mid, w2 + (size_t)l * 256 * FFz, fc2_b + l * Dz, nullptr,
            tok, tok, nullptr, nullptr, nullptr, Mp, Dz, FFz, FFz, Dz);
    }

    pool_norm_k<<<Bz, blk, 0, stream>>>(tok, fcn_s, fcn_b, pooledb);
    gemm2_k<0, 128><<<dim3(8, 1), blk, 0, stream>>>(
        pooledb, wh, head_b, nullptr, nullptr, out,
        nullptr, nullptr, nullptr, Bz, NCz, Kp, Kp, NCz);
}

// Round 8
// 2080.800 us; speedup vs baseline: 1.4971x; 1.0660x over previous
//
#include <hip/hip_runtime.h>
#include <math.h>

#define Bz 64
#define Tz 12000
#define Pz 50
#define Dz 200
#define Lz 12
#define Hz 10
#define HDz 20
#define FFz 800
#define Nz 240
#define Sz 241
#define Sp 256                // padded seq stride
#define NRDz 482
#define NCz 1000
#define BS (Bz * Sz)          // 15424 valid rows
#define Mp (Bz * Sp)          // 16384 padded rows
#define Kp 224                // K=200 padded to 7*32
#define SCALEq 0.22360679774997896f
#define LOG2E 1.4426950408889634f
#define SCALE2f (SCALEq * LOG2E)
#define BIASL 655360          // shorts per layer of bias table

typedef __attribute__((ext_vector_type(8))) short bf16x8;
typedef __attribute__((ext_vector_type(4))) float f32x4;

static __device__ __forceinline__ short f2b(float f) {
    unsigned u = __float_as_uint(f);
    unsigned r = (u + 0x7fffu + ((u >> 16) & 1u)) >> 16;
    return (short)r;
}
static __device__ __forceinline__ float b2f(short v) {
    return __uint_as_float(((unsigned)(unsigned short)v) << 16);
}
static __device__ __forceinline__ void gll16(const void* g, void* l) {
    __builtin_amdgcn_global_load_lds((const __attribute__((address_space(1))) unsigned*)g,
                                     (__attribute__((address_space(3))) unsigned*)l, 16, 0, 0);
}

// ---------------- f32 [L][N][K] -> bf16 [L][Npad][Kpad] zero-padded ----------------
__global__ void cvt_pad_k(const float* __restrict__ in, short* __restrict__ out,
                          int N, int K, int Npad, int Kpad, int total) {
    int i = blockIdx.x * 256 + threadIdx.x;
    if (i >= total) return;
    int pk = Npad * Kpad;
    int l = i / pk;
    int r = i - l * pk;
    int n = r / Kpad;
    int k = r - n * Kpad;
    float v = (n < N && k < K) ? in[((size_t)l * N + n) * K + k] : 0.f;
    out[i] = f2b(v);
}

// ---------------- patch embed -> tok padded rows ----------------
__global__ void patch_embed_k(const float* __restrict__ x, const float* __restrict__ cw,
                              const float* __restrict__ cb, const float* __restrict__ cls,
                              const float* __restrict__ pos, float* __restrict__ tok) {
    int bs = blockIdx.x;
    int b = bs / Sz, s = bs % Sz;
    int d = threadIdx.x;
    size_t row = (size_t)b * Sp + s;
    __shared__ float xp[Pz];
    if (s == 0) {
        if (d < Dz) tok[row * Dz + d] = cls[d] + pos[d];
        return;
    }
    if (d < Pz) xp[d] = x[(size_t)b * Tz + (s - 1) * Pz + d];
    __syncthreads();
    if (d < Dz) {
        float acc = cb[d];
        const float* w = cw + d * Pz;
        #pragma unroll
        for (int p = 0; p < Pz; ++p) acc += xp[p] * w[p];
        tok[row * Dz + d] = acc + pos[s * Dz + d];
    }
}

// ---------------- layernorm: f32 (padded rows, ld 200) -> bf16 (ld 224) ----------------
__global__ void ln_k(const float* __restrict__ in, short* __restrict__ out,
                     const float* __restrict__ sc, const float* __restrict__ bi) {
    int wave = threadIdx.x >> 6, lane = threadIdx.x & 63;
    int row = blockIdx.x * 4 + wave;
    if ((row & 255) >= Sz) return;
    const float* x = in + (size_t)row * Dz;
    float v[4];
    float sum = 0.f;
    #pragma unroll
    for (int i = 0; i < 4; ++i) {
        int d = lane + 64 * i;
        v[i] = (d < Dz) ? x[d] : 0.f;
        sum += v[i];
    }
    #pragma unroll
    for (int off = 32; off; off >>= 1) sum += __shfl_xor(sum, off);
    float mean = sum * (1.f / Dz);
    float var = 0.f;
    #pragma unroll
    for (int i = 0; i < 4; ++i) {
        int d = lane + 64 * i;
        if (d < Dz) { float t = v[i] - mean; var += t * t; }
    }
    #pragma unroll
    for (int off = 32; off; off >>= 1) var += __shfl_xor(var, off);
    var *= (1.f / Dz);
    float rstd = rsqrtf(var + 1e-6f);
    short* o = out + (size_t)row * Kp;
    #pragma unroll
    for (int i = 0; i < 4; ++i) {
        int d = lane + 64 * i;
        if (d < Dz) o[d] = f2b((v[i] - mean) * rstd * sc[d] + bi[d]);
        else if (d < Kp) o[d] = 0;
    }
}

// ---------------- bias precompute (ALL layers), swapped-fragment order ----------------
// short4 idx = lane + 64*mi + 128*w + 512*qb + 1024*nj + 4096*kc + 16384*h (+ layer*163840)
// q = qb*128 + w*32 + mi*16 + (lane&15);  k = kc*64 + nj*16 + 4*(lane>>4) + r
__global__ void bias_pre4_k(const float* __restrict__ tabs, short* __restrict__ bp) {
    int l = blockIdx.y;
    int tid = blockIdx.x * 256 + threadIdx.x;      // 163840 per layer
    const float* tab = tabs + (size_t)l * NRDz * Hz;
    int lane = tid & 63;
    int mi = (tid >> 6) & 1;
    int w  = (tid >> 7) & 3;
    int qb = (tid >> 9) & 1;
    int nj = (tid >> 10) & 3;
    int kc = (tid >> 12) & 3;
    int h  = tid >> 14;
    int q  = qb * 128 + w * 32 + mi * 16 + (lane & 15);
    int k0 = kc * 64 + nj * 16 + 4 * (lane >> 4);
    short4 o;
    #pragma unroll
    for (int r = 0; r < 4; ++r) {
        int k = k0 + r;
        float v;
        if (q > Nz || k > Nz) v = -1e30f;
        else if (k == 0)      v = (q == 0) ? tab[481 * Hz + h] : tab[480 * Hz + h];
        else if (q == 0)      v = tab[479 * Hz + h];
        else                  v = tab[(q - k + 239) * Hz + h];
        ((short*)&o)[r] = f2b(v * LOG2E);
    }
    *(short4*)(bp + (size_t)l * BIASL + (size_t)tid * 4) = o;
}

// ---------------- MFMA GEMM v3: double-buffered, prefetch-overlapped ----------------
// MODE 0: f32 +bias (head)   MODE 1: qkv -> Qb/Kb/Vtb (pre-scaled Q, swizzled K/Vt)
// MODE 2: f32 +bias+res      MODE 3: bf16 gelu(+bias)
template <int MODE, int BN2>
__global__ __launch_bounds__(256) void gemm3_k(
        const short* __restrict__ A, const short* __restrict__ W,
        const float* __restrict__ bias, const float* __restrict__ bias2,
        const float* __restrict__ res, void* __restrict__ outv,
        short* __restrict__ qo, short* __restrict__ ko, short* __restrict__ vo,
        int M, int Nreal, int K, int strideA, int ldo) {
    constexpr int NJ = BN2 / 32;
    constexpr int BISS = BN2 / 64;
    __shared__ short As[2][128 * 32];
    __shared__ short Bs[2][BN2 * 32];
    const int t = threadIdx.x;
    const int lane = t & 63, w = t >> 6;
    const int l15 = lane & 15, lg = lane >> 4;
    const int wm = w & 1, wn = w >> 1;
    const int row0 = blockIdx.y * 128, col0 = blockIdx.x * BN2;
    const int xsw = (l15 >> 1) & 3;

    // per-wave staging addresses (row/octet fixed per issue slot)
    f32x4 acc[4][NJ];
    #pragma unroll
    for (int mi = 0; mi < 4; ++mi)
        #pragma unroll
        for (int nj = 0; nj < NJ; ++nj) {
            f32x4 z = {0.f, 0.f, 0.f, 0.f};
            acc[mi][nj] = z;
        }

    const int nk = K >> 5;

    auto stage = [&](int buf, int kt) {
        const int k0 = kt * 32;
        #pragma unroll
        for (int i = 0; i < 2; ++i) {
            int c = (w * 2 + i) * 64 + lane;
            int r = c >> 2, q = c & 3;
            const short* gp = A + (size_t)(row0 + r) * strideA + k0 + ((q ^ ((r >> 1) & 3)) * 8);
            gll16(gp, As[buf] + (w * 2 + i) * 512);
        }
        #pragma unroll
        for (int i = 0; i < BISS; ++i) {
            int c = (w * BISS + i) * 64 + lane;
            int r = c >> 2, q = c & 3;
            const short* gp = W + (size_t)(col0 + r) * K + k0 + ((q ^ ((r >> 1) & 3)) * 8);
            gll16(gp, Bs[buf] + (w * BISS + i) * 512);
        }
    };

    stage(0, 0);
    __syncthreads();
    for (int kt = 0; kt < nk; ++kt) {
        const int cur = kt & 1;
        if (kt + 1 < nk) stage(cur ^ 1, kt + 1);   // prefetch overlaps compute
        bf16x8 bfr[NJ], afr[4];
        #pragma unroll
        for (int nj = 0; nj < NJ; ++nj)
            bfr[nj] = *(const bf16x8*)(Bs[cur] + (wn * (BN2 / 2) + nj * 16 + l15) * 32 + ((lg ^ xsw) * 8));
        #pragma unroll
        for (int mi = 0; mi < 4; ++mi)
            afr[mi] = *(const bf16x8*)(As[cur] + (wm * 64 + mi * 16 + l15) * 32 + ((lg ^ xsw) * 8));
        #pragma unroll
        for (int mi = 0; mi < 4; ++mi)
            #pragma unroll
            for (int nj = 0; nj < NJ; ++nj)
                acc[mi][nj] = __builtin_amdgcn_mfma_f32_16x16x32_bf16(afr[mi], bfr[nj], acc[mi][nj], 0, 0, 0);
        __syncthreads();    // drains prefetch (vmcnt0) + protects buffer swap
    }

    #pragma unroll
    for (int mi = 0; mi < 4; ++mi) {
        #pragma unroll
        for (int nj = 0; nj < NJ; ++nj) {
            int n = col0 + wn * (BN2 / 2) + nj * 16 + l15;
            if (n >= Nreal) continue;
            if (MODE == 1) {
                int which = n >= 400 ? 2 : (n >= 200 ? 1 : 0);
                int hd = n - which * 200;
                int h = hd / 20, d = hd - h * 20;
                int m0 = row0 + wm * 64 + mi * 16 + 4 * lg;
                int b = m0 >> 8, s0 = m0 & 255;
                size_t base = (size_t)(b * Hz + h) * 8192;
                if (which == 2) {
                    short4 o4;
                    float vb = bias2[hd];
                    #pragma unroll
                    for (int r = 0; r < 4; ++r)
                        ((short*)&o4)[r] = f2b(acc[mi][nj][r] + vb);
                    *(short4*)(vo + base + d * 256 + (s0 ^ ((d & 7) << 3))) = o4;
                } else if (which == 0) {
                    float qb = bias[hd];
                    #pragma unroll
                    for (int r = 0; r < 4; ++r)
                        qo[base + (s0 + r) * 32 + d] = f2b((acc[mi][nj][r] + qb) * SCALE2f);
                } else {
                    #pragma unroll
                    for (int r = 0; r < 4; ++r) {
                        int s = s0 + r;
                        ko[base + s * 32 + (((d >> 3) ^ ((s >> 1) & 3)) * 8) + (d & 7)] = f2b(acc[mi][nj][r]);
                    }
                }
            } else {
                #pragma unroll
                for (int r = 0; r < 4; ++r) {
                    int m = row0 + wm * 64 + mi * 16 + 4 * lg + r;
                    if (m >= M) continue;
                    float v = acc[mi][nj][r];
                    size_t off = (size_t)m * ldo + n;
                    if (MODE == 0) {
                        ((float*)outv)[off] = v + bias[n];
                    } else if (MODE == 2) {
                        ((float*)outv)[off] = v + bias[n] + res[off];
                    } else {
                        v += bias[n];
                        v = 0.5f * v * (1.f + erff(v * 0.70710678118654752f));
                        ((short*)outv)[off] = f2b(v);
                    }
                }
            }
        }
    }
}

// ---------------- MFMA attention v4: swapped QK^T (lane-local softmax rows) ----------------
// 1280 blocks: (bh, q-half). LDS: Ks 16KB + Vt 16KB + Pl 18KB = 50.25KB.
#define PLD 72
__global__ __launch_bounds__(256) void attn4_k(const short* __restrict__ Qb,
                                               const short* __restrict__ Kb,
                                               const short* __restrict__ Vtb,
                                               const short* __restrict__ biasC,
                                               short* __restrict__ o) {
    const int blk = blockIdx.x;
    const int qb = blk & 1;
    const int bh = blk >> 1;
    const int b = bh / Hz, h = bh - b * Hz;
    __shared__ short Ks[8192];
    __shared__ short Vt[8192];
    __shared__ short Pl[4][32 * PLD];
    const int t = threadIdx.x;
    const int lane = t & 63, w = t >> 6;
    const int l15 = lane & 15, lg = lane >> 4;

    const short* kbh = Kb + (size_t)bh * 8192;
    const short* vbh = Vtb + (size_t)bh * 8192;
    #pragma unroll
    for (int i = 0; i < 4; ++i) {
        int j = w * 4 + i;
        gll16(kbh + (size_t)(j * 64 + lane) * 8, Ks + j * 512);
        gll16(vbh + (size_t)(j * 64 + lane) * 8, Vt + j * 512);
    }
    bf16x8 qfrag[2];
    const short* qbh = Qb + (size_t)bh * 8192;
    #pragma unroll
    for (int mi = 0; mi < 2; ++mi) {
        int qrow = qb * 128 + w * 32 + mi * 16 + l15;
        qfrag[mi] = *(const bf16x8*)(qbh + qrow * 32 + lg * 8);
    }
    const short* bpp = biasC + 4 * (size_t)(lane + 128 * w + 512 * qb + 16384 * h);
    __syncthreads();

    f32x4 O[2][2];
    float mrow[2] = {-1e30f, -1e30f};
    float lrow[2] = {0.f, 0.f};
    {
        f32x4 z = {0.f, 0.f, 0.f, 0.f};
        O[0][0] = z; O[0][1] = z; O[1][0] = z; O[1][1] = z;
    }
    const int xsw = (l15 >> 1) & 3;

    #pragma unroll 1
    for (int kc = 0; kc < 4; ++kc) {
        bf16x8 kf[4];
        #pragma unroll
        for (int nj = 0; nj < 4; ++nj)
            kf[nj] = *(const bf16x8*)(Ks + (kc * 64 + nj * 16 + l15) * 32 + ((lg ^ xsw) * 8));
        // swapped: s rows = k (4*lg + r), cols = q (l15)
        f32x4 s[2][4];
        #pragma unroll
        for (int mi = 0; mi < 2; ++mi)
            #pragma unroll
            for (int nj = 0; nj < 4; ++nj) {
                f32x4 z = {0.f, 0.f, 0.f, 0.f};
                s[mi][nj] = __builtin_amdgcn_mfma_f32_16x16x32_bf16(kf[nj], qfrag[mi], z, 0, 0, 0);
            }
        const short* bkc = bpp + kc * 16384;
        #pragma unroll
        for (int mi = 0; mi < 2; ++mi)
            #pragma unroll
            for (int nj = 0; nj < 4; ++nj) {
                short4 bp4 = *(const short4*)(bkc + nj * 4096 + mi * 256);
                s[mi][nj][0] += b2f(bp4.x);
                s[mi][nj][1] += b2f(bp4.y);
                s[mi][nj][2] += b2f(bp4.z);
                s[mi][nj][3] += b2f(bp4.w);
            }
        #pragma unroll
        for (int mi = 0; mi < 2; ++mi) {
            // lane-local max over 16 k-values, then 2 shfl across lg groups
            float mx = s[mi][0][0];
            #pragma unroll
            for (int nj = 0; nj < 4; ++nj)
                #pragma unroll
                for (int c = 0; c < 4; ++c) mx = fmaxf(mx, s[mi][nj][c]);
            mx = fmaxf(mx, __shfl_xor(mx, 16));
            mx = fmaxf(mx, __shfl_xor(mx, 32));
            float mn = fmaxf(mrow[mi], mx);
            float scn = exp2f(mrow[mi] - mn);
            mrow[mi] = mn;
            float ssum = 0.f;
            #pragma unroll
            for (int nj = 0; nj < 4; ++nj)
                #pragma unroll
                for (int c = 0; c < 4; ++c) {
                    float p = exp2f(s[mi][nj][c] - mn);
                    s[mi][nj][c] = p;
                    ssum += p;
                }
            ssum += __shfl_xor(ssum, 16);
            ssum += __shfl_xor(ssum, 32);
            lrow[mi] = lrow[mi] * scn + ssum;
            // redistribute rescale factor to O-row layout (row q = 4*lg + r)
            f32x4 scd;
            #pragma unroll
            for (int r = 0; r < 4; ++r) scd[r] = __shfl(scn, 4 * lg + r);
            O[mi][0] *= scd;
            O[mi][1] *= scd;
            // write P (row q = l15, cols k), one b64 per nj
            #pragma unroll
            for (int nj = 0; nj < 4; ++nj) {
                short4 p4;
                #pragma unroll
                for (int r = 0; r < 4; ++r) ((short*)&p4)[r] = f2b(s[mi][nj][r]);
                *(short4*)(Pl[w] + (mi * 16 + l15) * PLD + nj * 16 + 4 * lg) = p4;
            }
        }
        // PV: two K=32 halves
        #pragma unroll
        for (int kk = 0; kk < 2; ++kk) {
            bf16x8 vf[2];
            #pragma unroll
            for (int dj = 0; dj < 2; ++dj) {
                int d = dj * 16 + l15;
                int cb = (kc * 128 + kk * 64 + lg * 16) ^ ((l15 & 7) << 4);
                vf[dj] = *(const bf16x8*)((const char*)Vt + d * 512 + cb);
            }
            #pragma unroll
            for (int mi = 0; mi < 2; ++mi) {
                bf16x8 af = *(const bf16x8*)(Pl[w] + (mi * 16 + l15) * PLD + kk * 32 + lg * 8);
                O[mi][0] = __builtin_amdgcn_mfma_f32_16x16x32_bf16(af, vf[0], O[mi][0], 0, 0, 0);
                O[mi][1] = __builtin_amdgcn_mfma_f32_16x16x32_bf16(af, vf[1], O[mi][1], 0, 0, 0);
            }
        }
    }

    #pragma unroll
    for (int mi = 0; mi < 2; ++mi) {
        float linv = 1.f / lrow[mi];
        f32x4 invd;
        #pragma unroll
        for (int r = 0; r < 4; ++r) invd[r] = __shfl(linv, 4 * lg + r);
        #pragma unroll
        for (int dj = 0; dj < 2; ++dj) {
            int d = dj * 16 + l15;
            if (d >= HDz) continue;
            #pragma unroll
            for (int r = 0; r < 4; ++r) {
                int q = qb * 128 + w * 32 + mi * 16 + 4 * lg + r;
                if (q < Sz)
                    o[((size_t)b * Sp + q) * Kp + h * HDz + d] = f2b(O[mi][dj][r] * invd[r]);
            }
        }
    }
}

// ---------------- pool + fc_norm -> bf16 pooled ----------------
__global__ void pool_norm_k(const float* __restrict__ tok, const float* __restrict__ sc,
                            const float* __restrict__ bi, short* __restrict__ pooled) {
    int b = blockIdx.x;
    int t = threadIdx.x;
    float val = 0.f;
    if (t < Dz) {
        const float* base = tok + ((size_t)b * Sp + 1) * Dz + t;
        float s = 0.f;
        for (int si = 0; si < Nz; ++si) s += base[(size_t)si * Dz];
        val = s * (1.f / Nz);
    }
    __shared__ float red[8];
    float sum = val, sq = val * val;
    #pragma unroll
    for (int off = 32; off; off >>= 1) { sum += __shfl_xor(sum, off); sq += __shfl_xor(sq, off); }
    int wave = t >> 6, lane = t & 63;
    if (lane == 0) { red[wave] = sum; red[4 + wave] = sq; }
    __syncthreads();
    sum = red[0] + red[1] + red[2] + red[3];
    sq = red[4] + red[5] + red[6] + red[7];
    float mean = sum * (1.f / Dz);
    float var = sq * (1.f / Dz) - mean * mean;
    float rstd = rsqrtf(var + 1e-6f);
    if (t < Dz) pooled[(size_t)b * Kp + t] = f2b((val - mean) * rstd * sc[t] + bi[t]);
    else if (t < Kp) pooled[(size_t)b * Kp + t] = 0;
}

extern "C" void kernel_launch(void* const* d_in, const int* in_sizes, int n_in,
                              void* d_out, int out_size, void* d_ws, size_t ws_size,
                              hipStream_t stream) {
    const float* x        = (const float*)d_in[0];
    const float* conv_w   = (const float*)d_in[1];
    const float* conv_b   = (const float*)d_in[2];
    const float* cls_tok  = (const float*)d_in[3];
    const float* pos_emb  = (const float*)d_in[4];
    const float* ln1_s    = (const float*)d_in[5];
    const float* ln1_b    = (const float*)d_in[6];
    const float* qkv_w    = (const float*)d_in[7];
    const float* q_bias   = (const float*)d_in[8];
    const float* v_bias   = (const float*)d_in[9];
    const float* rpb      = (const float*)d_in[10];
    const float* proj_w   = (const float*)d_in[11];
    const float* proj_b   = (const float*)d_in[12];
    const float* ln2_s    = (const float*)d_in[13];
    const float* ln2_b    = (const float*)d_in[14];
    const float* fc1_w    = (const float*)d_in[15];
    const float* fc1_b    = (const float*)d_in[16];
    const float* fc2_w    = (const float*)d_in[17];
    const float* fc2_b    = (const float*)d_in[18];
    const float* fcn_s    = (const float*)d_in[19];
    const float* fcn_b    = (const float*)d_in[20];
    const float* head_w   = (const float*)d_in[21];
    const float* head_b   = (const float*)d_in[22];
    float* out = (float*)d_out;

    char* ws = (char*)d_ws;
    float* tok  = (float*)ws;  ws += (size_t)Mp * Dz * 4;        // 13.11 MB
    short* xln  = (short*)ws;  ws += (size_t)Mp * Kp * 2;        // 7.34 MB
    short* mid  = (short*)ws;  ws += (size_t)Mp * FFz * 2;       // 26.21 MB
    short* Qb   = (short*)ws;  ws += (size_t)640 * 8192 * 2;     // 10.49 MB
    short* Kb   = (short*)ws;  ws += (size_t)640 * 8192 * 2;
    short* Vtb  = (short*)ws;  ws += (size_t)640 * 8192 * 2;
    short* wq = (short*)ws;    ws += (size_t)Lz * 640 * Kp * 2;
    short* wp = (short*)ws;    ws += (size_t)Lz * 256 * Kp * 2;
    short* w1 = (short*)ws;    ws += (size_t)Lz * 896 * Kp * 2;
    short* w2 = (short*)ws;    ws += (size_t)Lz * 256 * FFz * 2;
    short* wh = (short*)ws;    ws += (size_t)1024 * Kp * 2;
    short* biasC = (short*)ws; ws += (size_t)Lz * BIASL * 2;     // 15.7 MB
    short* pooledb = (short*)ws;

    hipMemsetAsync(xln, 0, (size_t)Mp * Kp * 2, stream);
    hipMemsetAsync(Qb, 0, (size_t)640 * 8192 * 2 * 3, stream);

    {
        int n;
        n = Lz * 640 * Kp;  cvt_pad_k<<<(n + 255) / 256, 256, 0, stream>>>(qkv_w, wq, 600, 200, 640, Kp, n);
        n = Lz * 256 * Kp;  cvt_pad_k<<<(n + 255) / 256, 256, 0, stream>>>(proj_w, wp, 200, 200, 256, Kp, n);
        n = Lz * 896 * Kp;  cvt_pad_k<<<(n + 255) / 256, 256, 0, stream>>>(fc1_w, w1, 800, 200, 896, Kp, n);
        n = Lz * 256 * FFz; cvt_pad_k<<<(n + 255) / 256, 256, 0, stream>>>(fc2_w, w2, 200, 800, 256, FFz, n);
        n = 1024 * Kp;      cvt_pad_k<<<(n + 255) / 256, 256, 0, stream>>>(head_w, wh, 1000, 200, 1024, Kp, n);
    }
    bias_pre4_k<<<dim3(640, Lz), 256, 0, stream>>>(rpb, biasC);

    patch_embed_k<<<BS, 256, 0, stream>>>(x, conv_w, conv_b, cls_tok, pos_emb, tok);

    dim3 blk(256);
    for (int l = 0; l < Lz; ++l) {
        ln_k<<<Mp / 4, blk, 0, stream>>>(tok, xln, ln1_s + l * Dz, ln1_b + l * Dz);
        gemm3_k<1, 128><<<dim3(5, Mp / 128), blk, 0, stream>>>(
            xln, wq + (size_t)l * 640 * Kp, q_bias + l * Dz, v_bias + l * Dz,
            nullptr, nullptr, Qb, Kb, Vtb, Mp, 600, Kp, Kp, 0);
        attn4_k<<<1280, blk, 0, stream>>>(Qb, Kb, Vtb, biasC + (size_t)l * BIASL, xln);
        gemm3_k<2, 64><<<dim3(4, Mp / 128), blk, 0, stream>>>(
            xln, wp + (size_t)l * 256 * Kp, proj_b + l * Dz, nullptr,
            tok, tok, nullptr, nullptr, nullptr, Mp, Dz, Kp, Kp, Dz);
        ln_k<<<Mp / 4, blk, 0, stream>>>(tok, xln, ln2_s + l * Dz, ln2_b + l * Dz);
        gemm3_k<3, 128><<<dim3(7, Mp / 128), blk, 0, stream>>>(
            xln, w1 + (size_t)l * 896 * Kp, fc1_b + l * FFz, nullptr,
            nullptr, mid, nullptr, nullptr, nullptr, Mp, FFz, Kp, Kp, FFz);
        gemm3_k<2, 64><<<dim3(4, Mp / 128), blk, 0, stream>>>(
            mid, w2 + (size_t)l * 256 * FFz, fc2_b + l * Dz, nullptr,
            tok, tok, nullptr, nullptr, nullptr, Mp, Dz, FFz, FFz, Dz);
    }

    pool_norm_k<<<Bz, blk, 0, stream>>>(tok, fcn_s, fcn_b, pooledb);
    gemm3_k<0, 128><<<dim3(8, 1), blk, 0, stream>>>(
        pooledb, wh, head_b, nullptr, nullptr, out,
        nullptr, nullptr, nullptr, Bz, NCz, Kp, Kp, NCz);
}

// Round 9
// 1943.996 us; speedup vs baseline: 1.6025x; 1.0704x over previous
//
#include <hip/hip_runtime.h>
#include <math.h>

#define Bz 64
#define Tz 12000
#define Pz 50
#define Dz 200
#define Lz 12
#define Hz 10
#define HDz 20
#define FFz 800
#define Nz 240
#define Sz 241
#define Sp 256                // padded seq stride
#define NRDz 482
#define NCz 1000
#define BS (Bz * Sz)          // 15424 valid rows
#define Mp (Bz * Sp)          // 16384 padded rows
#define Kp 224                // K=200 padded to 7*32
#define PEM (Bz * Nz)         // 15360 patch rows
#define SCALEq 0.22360679774997896f
#define LOG2E 1.4426950408889634f
#define SCALE2f (SCALEq * LOG2E)
#define BIASL 655360          // shorts per layer of bias table

typedef __attribute__((ext_vector_type(8))) short bf16x8;
typedef __attribute__((ext_vector_type(4))) float f32x4;

static __device__ __forceinline__ short f2b(float f) {
    unsigned u = __float_as_uint(f);
    unsigned r = (u + 0x7fffu + ((u >> 16) & 1u)) >> 16;
    return (short)r;
}
static __device__ __forceinline__ float b2f(short v) {
    return __uint_as_float(((unsigned)(unsigned short)v) << 16);
}
static __device__ __forceinline__ uint2 pk4(float a, float b, float c, float d) {
    uint2 r;
    asm("v_cvt_pk_bf16_f32 %0, %1, %2" : "=v"(r.x) : "v"(a), "v"(b));
    asm("v_cvt_pk_bf16_f32 %0, %1, %2" : "=v"(r.y) : "v"(c), "v"(d));
    return r;
}
static __device__ __forceinline__ void gll16(const void* g, void* l) {
    __builtin_amdgcn_global_load_lds((const __attribute__((address_space(1))) unsigned*)g,
                                     (__attribute__((address_space(3))) unsigned*)l, 16, 0, 0);
}

// ---------------- f32 [L][N][K] -> bf16 [L][Npad][Kpad] zero-padded ----------------
__global__ void cvt_pad_k(const float* __restrict__ in, short* __restrict__ out,
                          int N, int K, int Npad, int Kpad, int total) {
    int i = blockIdx.x * 256 + threadIdx.x;
    if (i >= total) return;
    int pk = Npad * Kpad;
    int l = i / pk;
    int r = i - l * pk;
    int n = r / Kpad;
    int k = r - n * Kpad;
    float v = (n < N && k < K) ? in[((size_t)l * N + n) * K + k] : 0.f;
    out[i] = f2b(v);
}

// ---------------- x -> bf16 patches [15360][64] (pad 50->64) ----------------
__global__ void xcvt_k(const float* __restrict__ x, short* __restrict__ xb) {
    int i = blockIdx.x * 256 + threadIdx.x;      // PEM*64
    int m = i >> 6, k = i & 63;
    int b = m / Nz, j = m - b * Nz;
    xb[i] = (k < Pz) ? f2b(x[(size_t)b * Tz + j * Pz + k]) : 0;
}

// ---------------- cls rows: tok[b*256][d] = cls[d] + pos[0][d] ----------------
__global__ void cls_k(const float* __restrict__ cls, const float* __restrict__ pos,
                      float* __restrict__ tok) {
    int b = blockIdx.x, d = threadIdx.x;
    if (d < Dz) tok[(size_t)b * Sp * Dz + d] = cls[d] + pos[d];
}

// ---------------- layernorm: f32 (padded rows, ld 200) -> bf16 (ld 224) ----------------
__global__ void ln_k(const float* __restrict__ in, short* __restrict__ out,
                     const float* __restrict__ sc, const float* __restrict__ bi) {
    int wave = threadIdx.x >> 6, lane = threadIdx.x & 63;
    int row = blockIdx.x * 4 + wave;
    if ((row & 255) >= Sz) return;
    const float* x = in + (size_t)row * Dz;
    float v[4];
    float sum = 0.f;
    #pragma unroll
    for (int i = 0; i < 4; ++i) {
        int d = lane + 64 * i;
        v[i] = (d < Dz) ? x[d] : 0.f;
        sum += v[i];
    }
    #pragma unroll
    for (int off = 32; off; off >>= 1) sum += __shfl_xor(sum, off);
    float mean = sum * (1.f / Dz);
    float var = 0.f;
    #pragma unroll
    for (int i = 0; i < 4; ++i) {
        int d = lane + 64 * i;
        if (d < Dz) { float t = v[i] - mean; var += t * t; }
    }
    #pragma unroll
    for (int off = 32; off; off >>= 1) var += __shfl_xor(var, off);
    var *= (1.f / Dz);
    float rstd = rsqrtf(var + 1e-6f);
    short* o = out + (size_t)row * Kp;
    #pragma unroll
    for (int i = 0; i < 4; ++i) {
        int d = lane + 64 * i;
        if (d < Dz) o[d] = f2b((v[i] - mean) * rstd * sc[d] + bi[d]);
        else if (d < Kp) o[d] = 0;
    }
}

// ---------------- bias precompute (ALL layers), swapped-fragment order ----------------
// short4 idx = lane + 64*mi + 128*w + 512*qb + 1024*nj + 4096*kc + 16384*h (+ layer*163840)
// q = qb*128 + w*32 + mi*16 + (lane&15);  k = kc*64 + nj*16 + 4*(lane>>4) + r
__global__ void bias_pre4_k(const float* __restrict__ tabs, short* __restrict__ bp) {
    int l = blockIdx.y;
    int tid = blockIdx.x * 256 + threadIdx.x;      // 163840 per layer
    const float* tab = tabs + (size_t)l * NRDz * Hz;
    int lane = tid & 63;
    int mi = (tid >> 6) & 1;
    int w  = (tid >> 7) & 3;
    int qb = (tid >> 9) & 1;
    int nj = (tid >> 10) & 3;
    int kc = (tid >> 12) & 3;
    int h  = tid >> 14;
    int q  = qb * 128 + w * 32 + mi * 16 + (lane & 15);
    int k0 = kc * 64 + nj * 16 + 4 * (lane >> 4);
    short4 o;
    #pragma unroll
    for (int r = 0; r < 4; ++r) {
        int k = k0 + r;
        float v;
        if (q > Nz || k > Nz) v = -1e30f;
        else if (k == 0)      v = (q == 0) ? tab[481 * Hz + h] : tab[480 * Hz + h];
        else if (q == 0)      v = tab[479 * Hz + h];
        else                  v = tab[(q - k + 239) * Hz + h];
        ((short*)&o)[r] = f2b(v * LOG2E);
    }
    *(short4*)(bp + (size_t)l * BIASL + (size_t)tid * 4) = o;
}

// ---------------- MFMA GEMM v3: double-buffered, prefetch-overlapped ----------------
// MODE 0: f32 +bias (head)   MODE 1: qkv -> Qb/Kb/Vtb (pre-scaled Q, swizzled K/Vt)
// MODE 2: f32 +bias+res      MODE 3: bf16 gelu(+bias)
// MODE 4: patch embed: f32 tok[b*256+j+1] = acc + conv_b + pos[j+1]
template <int MODE, int BN2>
__global__ __launch_bounds__(256) void gemm3_k(
        const short* __restrict__ A, const short* __restrict__ W,
        const float* __restrict__ bias, const float* __restrict__ bias2,
        const float* __restrict__ res, void* __restrict__ outv,
        short* __restrict__ qo, short* __restrict__ ko, short* __restrict__ vo,
        int M, int Nreal, int K, int strideA, int ldo) {
    constexpr int NJ = BN2 / 32;
    constexpr int BISS = BN2 / 64;
    __shared__ short As[2][128 * 32];
    __shared__ short Bs[2][BN2 * 32];
    const int t = threadIdx.x;
    const int lane = t & 63, w = t >> 6;
    const int l15 = lane & 15, lg = lane >> 4;
    const int wm = w & 1, wn = w >> 1;
    const int row0 = blockIdx.y * 128, col0 = blockIdx.x * BN2;
    const int xsw = (l15 >> 1) & 3;

    f32x4 acc[4][NJ];
    #pragma unroll
    for (int mi = 0; mi < 4; ++mi)
        #pragma unroll
        for (int nj = 0; nj < NJ; ++nj) {
            f32x4 z = {0.f, 0.f, 0.f, 0.f};
            acc[mi][nj] = z;
        }

    const int nk = K >> 5;

    auto stage = [&](int buf, int kt) {
        const int k0 = kt * 32;
        #pragma unroll
        for (int i = 0; i < 2; ++i) {
            int c = (w * 2 + i) * 64 + lane;
            int r = c >> 2, q = c & 3;
            const short* gp = A + (size_t)(row0 + r) * strideA + k0 + ((q ^ ((r >> 1) & 3)) * 8);
            gll16(gp, As[buf] + (w * 2 + i) * 512);
        }
        #pragma unroll
        for (int i = 0; i < BISS; ++i) {
            int c = (w * BISS + i) * 64 + lane;
            int r = c >> 2, q = c & 3;
            const short* gp = W + (size_t)(col0 + r) * K + k0 + ((q ^ ((r >> 1) & 3)) * 8);
            gll16(gp, Bs[buf] + (w * BISS + i) * 512);
        }
    };

    stage(0, 0);
    __syncthreads();
    for (int kt = 0; kt < nk; ++kt) {
        const int cur = kt & 1;
        if (kt + 1 < nk) stage(cur ^ 1, kt + 1);
        bf16x8 bfr[NJ], afr[4];
        #pragma unroll
        for (int nj = 0; nj < NJ; ++nj)
            bfr[nj] = *(const bf16x8*)(Bs[cur] + (wn * (BN2 / 2) + nj * 16 + l15) * 32 + ((lg ^ xsw) * 8));
        #pragma unroll
        for (int mi = 0; mi < 4; ++mi)
            afr[mi] = *(const bf16x8*)(As[cur] + (wm * 64 + mi * 16 + l15) * 32 + ((lg ^ xsw) * 8));
        #pragma unroll
        for (int mi = 0; mi < 4; ++mi)
            #pragma unroll
            for (int nj = 0; nj < NJ; ++nj)
                acc[mi][nj] = __builtin_amdgcn_mfma_f32_16x16x32_bf16(afr[mi], bfr[nj], acc[mi][nj], 0, 0, 0);
        __syncthreads();
    }

    #pragma unroll
    for (int mi = 0; mi < 4; ++mi) {
        #pragma unroll
        for (int nj = 0; nj < NJ; ++nj) {
            int n = col0 + wn * (BN2 / 2) + nj * 16 + l15;
            if (n >= Nreal) continue;
            if (MODE == 1) {
                int which = n >= 400 ? 2 : (n >= 200 ? 1 : 0);
                int hd = n - which * 200;
                int h = hd / 20, d = hd - h * 20;
                int m0 = row0 + wm * 64 + mi * 16 + 4 * lg;
                int b = m0 >> 8, s0 = m0 & 255;
                size_t base = (size_t)(b * Hz + h) * 8192;
                if (which == 2) {
                    short4 o4;
                    float vb = bias2[hd];
                    #pragma unroll
                    for (int r = 0; r < 4; ++r)
                        ((short*)&o4)[r] = f2b(acc[mi][nj][r] + vb);
                    *(short4*)(vo + base + d * 256 + (s0 ^ ((d & 7) << 3))) = o4;
                } else if (which == 0) {
                    float qb = bias[hd];
                    #pragma unroll
                    for (int r = 0; r < 4; ++r)
                        qo[base + (s0 + r) * 32 + d] = f2b((acc[mi][nj][r] + qb) * SCALE2f);
                } else {
                    #pragma unroll
                    for (int r = 0; r < 4; ++r) {
                        int s = s0 + r;
                        ko[base + s * 32 + (((d >> 3) ^ ((s >> 1) & 3)) * 8) + (d & 7)] = f2b(acc[mi][nj][r]);
                    }
                }
            } else if (MODE == 4) {
                #pragma unroll
                for (int r = 0; r < 4; ++r) {
                    int m = row0 + wm * 64 + mi * 16 + 4 * lg + r;
                    int bb = m / Nz, j = m - bb * Nz;
                    size_t trow = (size_t)bb * Sp + j + 1;
                    ((float*)outv)[trow * ldo + n] =
                        acc[mi][nj][r] + bias[n] + res[(size_t)(j + 1) * Dz + n];
                }
            } else {
                #pragma unroll
                for (int r = 0; r < 4; ++r) {
                    int m = row0 + wm * 64 + mi * 16 + 4 * lg + r;
                    if (m >= M) continue;
                    float v = acc[mi][nj][r];
                    size_t off = (size_t)m * ldo + n;
                    if (MODE == 0) {
                        ((float*)outv)[off] = v + bias[n];
                    } else if (MODE == 2) {
                        ((float*)outv)[off] = v + bias[n] + res[off];
                    } else {
                        v += bias[n];
                        v = 0.5f * v * (1.f + erff(v * 0.70710678118654752f));
                        ((short*)outv)[off] = f2b(v);
                    }
                }
            }
        }
    }
}

// ---------------- MFMA attention v5: swapped QK^T + defer-max + cvt_pk + setprio --------
// 1280 blocks: (bh, q-half). LDS: Ks 16KB + Vt 16KB + Pl 18KB = 50.25KB.
#define PLD 72
__global__ __launch_bounds__(256) void attn5_k(const short* __restrict__ Qb,
                                               const short* __restrict__ Kb,
                                               const short* __restrict__ Vtb,
                                               const short* __restrict__ biasC,
                                               short* __restrict__ o) {
    const int blk = blockIdx.x;
    const int qb = blk & 1;
    const int bh = blk >> 1;
    const int b = bh / Hz, h = bh - b * Hz;
    __shared__ short Ks[8192];
    __shared__ short Vt[8192];
    __shared__ short Pl[4][32 * PLD];
    const int t = threadIdx.x;
    const int lane = t & 63, w = t >> 6;
    const int l15 = lane & 15, lg = lane >> 4;

    const short* kbh = Kb + (size_t)bh * 8192;
    const short* vbh = Vtb + (size_t)bh * 8192;
    #pragma unroll
    for (int i = 0; i < 4; ++i) {
        int j = w * 4 + i;
        gll16(kbh + (size_t)(j * 64 + lane) * 8, Ks + j * 512);
        gll16(vbh + (size_t)(j * 64 + lane) * 8, Vt + j * 512);
    }
    bf16x8 qfrag[2];
    const short* qbh = Qb + (size_t)bh * 8192;
    #pragma unroll
    for (int mi = 0; mi < 2; ++mi) {
        int qrow = qb * 128 + w * 32 + mi * 16 + l15;
        qfrag[mi] = *(const bf16x8*)(qbh + qrow * 32 + lg * 8);
    }
    const short* bpp = biasC + 4 * (size_t)(lane + 128 * w + 512 * qb + 16384 * h);
    __syncthreads();

    f32x4 O[2][2];
    float mrow[2] = {-1e30f, -1e30f};
    float lrow[2] = {0.f, 0.f};
    {
        f32x4 z = {0.f, 0.f, 0.f, 0.f};
        O[0][0] = z; O[0][1] = z; O[1][0] = z; O[1][1] = z;
    }
    const int xsw = (l15 >> 1) & 3;

    #pragma unroll 1
    for (int kc = 0; kc < 4; ++kc) {
        bf16x8 kf[4];
        #pragma unroll
        for (int nj = 0; nj < 4; ++nj)
            kf[nj] = *(const bf16x8*)(Ks + (kc * 64 + nj * 16 + l15) * 32 + ((lg ^ xsw) * 8));
        // swapped: s rows = k (4*lg + r), cols = q (l15)
        f32x4 s[2][4];
        __builtin_amdgcn_s_setprio(1);
        #pragma unroll
        for (int mi = 0; mi < 2; ++mi)
            #pragma unroll
            for (int nj = 0; nj < 4; ++nj) {
                f32x4 z = {0.f, 0.f, 0.f, 0.f};
                s[mi][nj] = __builtin_amdgcn_mfma_f32_16x16x32_bf16(kf[nj], qfrag[mi], z, 0, 0, 0);
            }
        __builtin_amdgcn_s_setprio(0);
        const short* bkc = bpp + kc * 16384;
        #pragma unroll
        for (int mi = 0; mi < 2; ++mi)
            #pragma unroll
            for (int nj = 0; nj < 4; ++nj) {
                short4 bp4 = *(const short4*)(bkc + nj * 4096 + mi * 256);
                s[mi][nj][0] += b2f(bp4.x);
                s[mi][nj][1] += b2f(bp4.y);
                s[mi][nj][2] += b2f(bp4.z);
                s[mi][nj][3] += b2f(bp4.w);
            }
        #pragma unroll
        for (int mi = 0; mi < 2; ++mi) {
            float mx = s[mi][0][0];
            #pragma unroll
            for (int nj = 0; nj < 4; ++nj)
                #pragma unroll
                for (int c = 0; c < 4; ++c) mx = fmaxf(mx, s[mi][nj][c]);
            mx = fmaxf(mx, __shfl_xor(mx, 16));
            mx = fmaxf(mx, __shfl_xor(mx, 32));
            float ssum = 0.f;
            if (__all(mx - mrow[mi] <= 8.f)) {
                // deferred-max fast path: keep running max, no O rescale
                float mn = mrow[mi];
                #pragma unroll
                for (int nj = 0; nj < 4; ++nj)
                    #pragma unroll
                    for (int c = 0; c < 4; ++c) {
                        float p = exp2f(s[mi][nj][c] - mn);
                        s[mi][nj][c] = p;
                        ssum += p;
                    }
                ssum += __shfl_xor(ssum, 16);
                ssum += __shfl_xor(ssum, 32);
                lrow[mi] += ssum;
            } else {
                float mn = fmaxf(mrow[mi], mx);
                float scn = exp2f(mrow[mi] - mn);
                mrow[mi] = mn;
                #pragma unroll
                for (int nj = 0; nj < 4; ++nj)
                    #pragma unroll
                    for (int c = 0; c < 4; ++c) {
                        float p = exp2f(s[mi][nj][c] - mn);
                        s[mi][nj][c] = p;
                        ssum += p;
                    }
                ssum += __shfl_xor(ssum, 16);
                ssum += __shfl_xor(ssum, 32);
                lrow[mi] = lrow[mi] * scn + ssum;
                f32x4 scd;
                #pragma unroll
                for (int r = 0; r < 4; ++r) scd[r] = __shfl(scn, 4 * lg + r);
                O[mi][0] *= scd;
                O[mi][1] *= scd;
            }
            // P store (row q = l15, cols k), cvt_pk pairs -> one 8B store per nj
            #pragma unroll
            for (int nj = 0; nj < 4; ++nj)
                *(uint2*)(Pl[w] + (mi * 16 + l15) * PLD + nj * 16 + 4 * lg) =
                    pk4(s[mi][nj][0], s[mi][nj][1], s[mi][nj][2], s[mi][nj][3]);
        }
        // PV: two K=32 halves
        #pragma unroll
        for (int kk = 0; kk < 2; ++kk) {
            bf16x8 vf[2];
            #pragma unroll
            for (int dj = 0; dj < 2; ++dj) {
                int d = dj * 16 + l15;
                int cb = (kc * 128 + kk * 64 + lg * 16) ^ ((l15 & 7) << 4);
                vf[dj] = *(const bf16x8*)((const char*)Vt + d * 512 + cb);
            }
            __builtin_amdgcn_s_setprio(1);
            #pragma unroll
            for (int mi = 0; mi < 2; ++mi) {
                bf16x8 af = *(const bf16x8*)(Pl[w] + (mi * 16 + l15) * PLD + kk * 32 + lg * 8);
                O[mi][0] = __builtin_amdgcn_mfma_f32_16x16x32_bf16(af, vf[0], O[mi][0], 0, 0, 0);
                O[mi][1] = __builtin_amdgcn_mfma_f32_16x16x32_bf16(af, vf[1], O[mi][1], 0, 0, 0);
            }
            __builtin_amdgcn_s_setprio(0);
        }
    }

    #pragma unroll
    for (int mi = 0; mi < 2; ++mi) {
        float linv = 1.f / lrow[mi];
        f32x4 invd;
        #pragma unroll
        for (int r = 0; r < 4; ++r) invd[r] = __shfl(linv, 4 * lg + r);
        #pragma unroll
        for (int dj = 0; dj < 2; ++dj) {
            int d = dj * 16 + l15;
            if (d >= HDz) continue;
            #pragma unroll
            for (int r = 0; r < 4; ++r) {
                int q = qb * 128 + w * 32 + mi * 16 + 4 * lg + r;
                if (q < Sz)
                    o[((size_t)b * Sp + q) * Kp + h * HDz + d] = f2b(O[mi][dj][r] * invd[r]);
            }
        }
    }
}

// ---------------- pool + fc_norm -> bf16 pooled ----------------
__global__ void pool_norm_k(const float* __restrict__ tok, const float* __restrict__ sc,
                            const float* __restrict__ bi, short* __restrict__ pooled) {
    int b = blockIdx.x;
    int t = threadIdx.x;
    float val = 0.f;
    if (t < Dz) {
        const float* base = tok + ((size_t)b * Sp + 1) * Dz + t;
        float s = 0.f;
        for (int si = 0; si < Nz; ++si) s += base[(size_t)si * Dz];
        val = s * (1.f / Nz);
    }
    __shared__ float red[8];
    float sum = val, sq = val * val;
    #pragma unroll
    for (int off = 32; off; off >>= 1) { sum += __shfl_xor(sum, off); sq += __shfl_xor(sq, off); }
    int wave = t >> 6, lane = t & 63;
    if (lane == 0) { red[wave] = sum; red[4 + wave] = sq; }
    __syncthreads();
    sum = red[0] + red[1] + red[2] + red[3];
    sq = red[4] + red[5] + red[6] + red[7];
    float mean = sum * (1.f / Dz);
    float var = sq * (1.f / Dz) - mean * mean;
    float rstd = rsqrtf(var + 1e-6f);
    if (t < Dz) pooled[(size_t)b * Kp + t] = f2b((val - mean) * rstd * sc[t] + bi[t]);
    else if (t < Kp) pooled[(size_t)b * Kp + t] = 0;
}

extern "C" void kernel_launch(void* const* d_in, const int* in_sizes, int n_in,
                              void* d_out, int out_size, void* d_ws, size_t ws_size,
                              hipStream_t stream) {
    const float* x        = (const float*)d_in[0];
    const float* conv_w   = (const float*)d_in[1];
    const float* conv_b   = (const float*)d_in[2];
    const float* cls_tok  = (const float*)d_in[3];
    const float* pos_emb  = (const float*)d_in[4];
    const float* ln1_s    = (const float*)d_in[5];
    const float* ln1_b    = (const float*)d_in[6];
    const float* qkv_w    = (const float*)d_in[7];
    const float* q_bias   = (const float*)d_in[8];
    const float* v_bias   = (const float*)d_in[9];
    const float* rpb      = (const float*)d_in[10];
    const float* proj_w   = (const float*)d_in[11];
    const float* proj_b   = (const float*)d_in[12];
    const float* ln2_s    = (const float*)d_in[13];
    const float* ln2_b    = (const float*)d_in[14];
    const float* fc1_w    = (const float*)d_in[15];
    const float* fc1_b    = (const float*)d_in[16];
    const float* fc2_w    = (const float*)d_in[17];
    const float* fc2_b    = (const float*)d_in[18];
    const float* fcn_s    = (const float*)d_in[19];
    const float* fcn_b    = (const float*)d_in[20];
    const float* head_w   = (const float*)d_in[21];
    const float* head_b   = (const float*)d_in[22];
    float* out = (float*)d_out;

    char* ws = (char*)d_ws;
    float* tok  = (float*)ws;  ws += (size_t)Mp * Dz * 4;        // 13.11 MB
    short* xln  = (short*)ws;  ws += (size_t)Mp * Kp * 2;        // 7.34 MB
    short* mid  = (short*)ws;  ws += (size_t)Mp * FFz * 2;       // 26.21 MB
    short* Qb   = (short*)ws;  ws += (size_t)640 * 8192 * 2;     // 10.49 MB
    short* Kb   = (short*)ws;  ws += (size_t)640 * 8192 * 2;
    short* Vtb  = (short*)ws;  ws += (size_t)640 * 8192 * 2;
    short* wq = (short*)ws;    ws += (size_t)Lz * 640 * Kp * 2;
    short* wp = (short*)ws;    ws += (size_t)Lz * 256 * Kp * 2;
    short* w1 = (short*)ws;    ws += (size_t)Lz * 896 * Kp * 2;
    short* w2 = (short*)ws;    ws += (size_t)Lz * 256 * FFz * 2;
    short* wh = (short*)ws;    ws += (size_t)1024 * Kp * 2;
    short* biasC = (short*)ws; ws += (size_t)Lz * BIASL * 2;     // 15.7 MB
    short* xb   = (short*)ws;  ws += (size_t)PEM * 64 * 2;       // 1.97 MB
    short* wpe  = (short*)ws;  ws += (size_t)256 * 64 * 2;
    short* pooledb = (short*)ws;

    hipMemsetAsync(xln, 0, (size_t)Mp * Kp * 2, stream);
    hipMemsetAsync(Qb, 0, (size_t)640 * 8192 * 2 * 3, stream);

    {
        int n;
        n = Lz * 640 * Kp;  cvt_pad_k<<<(n + 255) / 256, 256, 0, stream>>>(qkv_w, wq, 600, 200, 640, Kp, n);
        n = Lz * 256 * Kp;  cvt_pad_k<<<(n + 255) / 256, 256, 0, stream>>>(proj_w, wp, 200, 200, 256, Kp, n);
        n = Lz * 896 * Kp;  cvt_pad_k<<<(n + 255) / 256, 256, 0, stream>>>(fc1_w, w1, 800, 200, 896, Kp, n);
        n = Lz * 256 * FFz; cvt_pad_k<<<(n + 255) / 256, 256, 0, stream>>>(fc2_w, w2, 200, 800, 256, FFz, n);
        n = 1024 * Kp;      cvt_pad_k<<<(n + 255) / 256, 256, 0, stream>>>(head_w, wh, 1000, 200, 1024, Kp, n);
        n = 256 * 64;       cvt_pad_k<<<(n + 255) / 256, 256, 0, stream>>>(conv_w, wpe, 200, 50, 256, 64, n);
    }
    bias_pre4_k<<<dim3(640, Lz), 256, 0, stream>>>(rpb, biasC);

    // patch embed as MFMA GEMM: tok[b*256+j+1] = patches @ conv_w^T + conv_b + pos
    xcvt_k<<<(PEM * 64) / 256, 256, 0, stream>>>(x, xb);
    gemm3_k<4, 64><<<dim3(4, PEM / 128), 256, 0, stream>>>(
        xb, wpe, conv_b, nullptr, pos_emb, tok,
        nullptr, nullptr, nullptr, PEM, Dz, 64, 64, Dz);
    cls_k<<<Bz, 256, 0, stream>>>(cls_tok, pos_emb, tok);

    dim3 blk(256);
    for (int l = 0; l < Lz; ++l) {
        ln_k<<<Mp / 4, blk, 0, stream>>>(tok, xln, ln1_s + l * Dz, ln1_b + l * Dz);
        gemm3_k<1, 128><<<dim3(5, Mp / 128), blk, 0, stream>>>(
            xln, wq + (size_t)l * 640 * Kp, q_bias + l * Dz, v_bias + l * Dz,
            nullptr, nullptr, Qb, Kb, Vtb, Mp, 600, Kp, Kp, 0);
        attn5_k<<<1280, blk, 0, stream>>>(Qb, Kb, Vtb, biasC + (size_t)l * BIASL, xln);
        gemm3_k<2, 64><<<dim3(4, Mp / 128), blk, 0, stream>>>(
            xln, wp + (size_t)l * 256 * Kp, proj_b + l * Dz, nullptr,
            tok, tok, nullptr, nullptr, nullptr, Mp, Dz, Kp, Kp, Dz);
        ln_k<<<Mp / 4, blk, 0, stream>>>(tok, xln, ln2_s + l * Dz, ln2_b + l * Dz);
        gemm3_k<3, 128><<<dim3(7, Mp / 128), blk, 0, stream>>>(
            xln, w1 + (size_t)l * 896 * Kp, fc1_b + l * FFz, nullptr,
            nullptr, mid, nullptr, nullptr, nullptr, Mp, FFz, Kp, Kp, FFz);
        gemm3_k<2, 64><<<dim3(4, Mp / 128), blk, 0, stream>>>(
            mid, w2 + (size_t)l * 256 * FFz, fc2_b + l * Dz, nullptr,
            tok, tok, nullptr, nullptr, nullptr, Mp, Dz, FFz, FFz, Dz);
    }

    pool_norm_k<<<Bz, blk, 0, stream>>>(tok, fcn_s, fcn_b, pooledb);
    gemm3_k<0, 128><<<dim3(8, 1), blk, 0, stream>>>(
        pooledb, wh, head_b, nullptr, nullptr, out,
        nullptr, nullptr, nullptr, Bz, NCz, Kp, Kp, NCz);
}

// Round 10
// 1599.920 us; speedup vs baseline: 1.9471x; 1.2151x over previous
//
#include <hip/hip_runtime.h>
#include <math.h>

#define Bz 64
#define Tz 12000
#define Pz 50
#define Dz 200
#define Lz 12
#define Hz 10
#define HDz 20
#define FFz 800
#define Nz 240
#define Sz 241
#define Sp 256                // padded seq stride
#define NRDz 482
#define NCz 1000
#define BS (Bz * Sz)          // 15424 valid rows
#define Mp (Bz * Sp)          // 16384 padded rows
#define Kp 224                // K=200 padded to 7*32
#define PEM (Bz * Nz)         // 15360 patch rows
#define SCALEq 0.22360679774997896f
#define LOG2E 1.4426950408889634f
#define SCALE2f (SCALEq * LOG2E)
#define BIASL 655360          // shorts per layer of bias table

typedef __attribute__((ext_vector_type(8))) short bf16x8;
typedef __attribute__((ext_vector_type(4))) float f32x4;

static __device__ __forceinline__ short f2b(float f) {
    unsigned u = __float_as_uint(f);
    unsigned r = (u + 0x7fffu + ((u >> 16) & 1u)) >> 16;
    return (short)r;
}
static __device__ __forceinline__ float b2f(short v) {
    return __uint_as_float(((unsigned)(unsigned short)v) << 16);
}
static __device__ __forceinline__ uint2 pk4(float a, float b, float c, float d) {
    uint2 r;
    asm("v_cvt_pk_bf16_f32 %0, %1, %2" : "=v"(r.x) : "v"(a), "v"(b));
    asm("v_cvt_pk_bf16_f32 %0, %1, %2" : "=v"(r.y) : "v"(c), "v"(d));
    return r;
}
static __device__ __forceinline__ float frcp(float x) {
    float r;
    asm("v_rcp_f32 %0, %1" : "=v"(r) : "v"(x));
    return r;
}
// gelu exact-erf replaced by tanh form (max abs diff ~3e-4, << bf16 rounding)
static __device__ __forceinline__ float gelu_f(float v) {
    float u = v * (0.7978845608f + 0.03567740814f * v * v);   // 0.79788456*(v+0.044715 v^3)
    float e = exp2f(2.885390082f * u);                         // e^{2u}
    return v * e * frcp(e + 1.f);                              // v * sigmoid(2u)
}
static __device__ __forceinline__ void gll16(const void* g, void* l) {
    __builtin_amdgcn_global_load_lds((const __attribute__((address_space(1))) unsigned*)g,
                                     (__attribute__((address_space(3))) unsigned*)l, 16, 0, 0);
}

// ---------------- f32 [L][N][K] -> bf16 [L][Npad][Kpad] zero-padded ----------------
__global__ void cvt_pad_k(const float* __restrict__ in, short* __restrict__ out,
                          int N, int K, int Npad, int Kpad, int total) {
    int i = blockIdx.x * 256 + threadIdx.x;
    if (i >= total) return;
    int pk = Npad * Kpad;
    int l = i / pk;
    int r = i - l * pk;
    int n = r / Kpad;
    int k = r - n * Kpad;
    float v = (n < N && k < K) ? in[((size_t)l * N + n) * K + k] : 0.f;
    out[i] = f2b(v);
}

// ---------------- x -> bf16 patches [15360][64] (pad 50->64) ----------------
__global__ void xcvt_k(const float* __restrict__ x, short* __restrict__ xb) {
    int i = blockIdx.x * 256 + threadIdx.x;      // PEM*64
    int m = i >> 6, k = i & 63;
    int b = m / Nz, j = m - b * Nz;
    xb[i] = (k < Pz) ? f2b(x[(size_t)b * Tz + j * Pz + k]) : 0;
}

// ---------------- cls rows: tok[b*256][d] = cls[d] + pos[0][d] ----------------
__global__ void cls_k(const float* __restrict__ cls, const float* __restrict__ pos,
                      float* __restrict__ tok) {
    int b = blockIdx.x, d = threadIdx.x;
    if (d < Dz) tok[(size_t)b * Sp * Dz + d] = cls[d] + pos[d];
}

// ---------------- layernorm: f32 (padded rows, ld 200) -> bf16 (ld 224) ----------------
__global__ void ln_k(const float* __restrict__ in, short* __restrict__ out,
                     const float* __restrict__ sc, const float* __restrict__ bi) {
    int wave = threadIdx.x >> 6, lane = threadIdx.x & 63;
    int row = blockIdx.x * 4 + wave;
    if ((row & 255) >= Sz) return;
    const float* x = in + (size_t)row * Dz;
    float v[4];
    float sum = 0.f;
    #pragma unroll
    for (int i = 0; i < 4; ++i) {
        int d = lane + 64 * i;
        v[i] = (d < Dz) ? x[d] : 0.f;
        sum += v[i];
    }
    #pragma unroll
    for (int off = 32; off; off >>= 1) sum += __shfl_xor(sum, off);
    float mean = sum * (1.f / Dz);
    float var = 0.f;
    #pragma unroll
    for (int i = 0; i < 4; ++i) {
        int d = lane + 64 * i;
        if (d < Dz) { float t = v[i] - mean; var += t * t; }
    }
    #pragma unroll
    for (int off = 32; off; off >>= 1) var += __shfl_xor(var, off);
    var *= (1.f / Dz);
    float rstd = rsqrtf(var + 1e-6f);
    short* o = out + (size_t)row * Kp;
    #pragma unroll
    for (int i = 0; i < 4; ++i) {
        int d = lane + 64 * i;
        if (d < Dz) o[d] = f2b((v[i] - mean) * rstd * sc[d] + bi[d]);
        else if (d < Kp) o[d] = 0;
    }
}

// ---------------- bias precompute (ALL layers), swapped-fragment order ----------------
// short4 idx = lane + 64*mi + 128*w + 512*qb + 1024*nj + 4096*kc + 16384*h (+ layer*163840)
// q = qb*128 + w*32 + mi*16 + (lane&15);  k = kc*64 + nj*16 + 4*(lane>>4) + r
__global__ void bias_pre4_k(const float* __restrict__ tabs, short* __restrict__ bp) {
    int l = blockIdx.y;
    int tid = blockIdx.x * 256 + threadIdx.x;      // 163840 per layer
    const float* tab = tabs + (size_t)l * NRDz * Hz;
    int lane = tid & 63;
    int mi = (tid >> 6) & 1;
    int w  = (tid >> 7) & 3;
    int qb = (tid >> 9) & 1;
    int nj = (tid >> 10) & 3;
    int kc = (tid >> 12) & 3;
    int h  = tid >> 14;
    int q  = qb * 128 + w * 32 + mi * 16 + (lane & 15);
    int k0 = kc * 64 + nj * 16 + 4 * (lane >> 4);
    short4 o;
    #pragma unroll
    for (int r = 0; r < 4; ++r) {
        int k = k0 + r;
        float v;
        if (q > Nz || k > Nz) v = -1e30f;
        else if (k == 0)      v = (q == 0) ? tab[481 * Hz + h] : tab[480 * Hz + h];
        else if (q == 0)      v = tab[479 * Hz + h];
        else                  v = tab[(q - k + 239) * Hz + h];
        ((short*)&o)[r] = f2b(v * LOG2E);
    }
    *(short4*)(bp + (size_t)l * BIASL + (size_t)tid * 4) = o;
}

// ---------------- MFMA GEMM v4: dbuf + prefetch + XCD-aware swizzle ----------------
// 1D grid (gridx*gridy); same-row blocks co-located per XCD for A-tile L2 sharing.
// MODE 0: f32 +bias (head)   MODE 1: qkv -> Qb/Kb/Vtb   MODE 2: f32 +bias+res
// MODE 3: bf16 gelu(+bias)   MODE 4: patch embed
template <int MODE, int BN2, int BM2>
__global__ __launch_bounds__(256) void gemm4_k(
        const short* __restrict__ A, const short* __restrict__ W,
        const float* __restrict__ bias, const float* __restrict__ bias2,
        const float* __restrict__ res, void* __restrict__ outv,
        short* __restrict__ qo, short* __restrict__ ko, short* __restrict__ vo,
        int M, int Nreal, int K, int strideA, int ldo, int gridx, int gridy) {
    constexpr int NJ = BN2 / 32;
    constexpr int MI = BM2 / 32;
    constexpr int AISS = BM2 / 64;
    constexpr int BISS = BN2 / 64;
    __shared__ short As[2][BM2 * 32];
    __shared__ short Bs[2][BN2 * 32];
    const int t = threadIdx.x;
    const int lane = t & 63, w = t >> 6;
    const int l15 = lane & 15, lg = lane >> 4;
    const int wm = w & 1, wn = w >> 1;

    int bx, by;
    {
        int wg = blockIdx.x;
        if ((gridy & 7) == 0) {
            int xcd = wg & 7, j = wg >> 3;
            bx = j % gridx;
            by = (j / gridx) * 8 + xcd;
        } else {
            bx = wg % gridx;
            by = wg / gridx;
        }
    }
    const int row0 = by * BM2, col0 = bx * BN2;
    const int xsw = (l15 >> 1) & 3;

    f32x4 acc[MI][NJ];
    #pragma unroll
    for (int mi = 0; mi < MI; ++mi)
        #pragma unroll
        for (int nj = 0; nj < NJ; ++nj) {
            f32x4 z = {0.f, 0.f, 0.f, 0.f};
            acc[mi][nj] = z;
        }

    const int nk = K >> 5;

    auto stage = [&](int buf, int kt) {
        const int k0 = kt * 32;
        #pragma unroll
        for (int i = 0; i < AISS; ++i) {
            int c = (w * AISS + i) * 64 + lane;
            int r = c >> 2, q = c & 3;
            const short* gp = A + (size_t)(row0 + r) * strideA + k0 + ((q ^ ((r >> 1) & 3)) * 8);
            gll16(gp, As[buf] + (w * AISS + i) * 512);
        }
        #pragma unroll
        for (int i = 0; i < BISS; ++i) {
            int c = (w * BISS + i) * 64 + lane;
            int r = c >> 2, q = c & 3;
            const short* gp = W + (size_t)(col0 + r) * K + k0 + ((q ^ ((r >> 1) & 3)) * 8);
            gll16(gp, Bs[buf] + (w * BISS + i) * 512);
        }
    };

    stage(0, 0);
    __syncthreads();
    for (int kt = 0; kt < nk; ++kt) {
        const int cur = kt & 1;
        if (kt + 1 < nk) stage(cur ^ 1, kt + 1);
        bf16x8 bfr[NJ], afr[MI];
        #pragma unroll
        for (int nj = 0; nj < NJ; ++nj)
            bfr[nj] = *(const bf16x8*)(Bs[cur] + (wn * (BN2 / 2) + nj * 16 + l15) * 32 + ((lg ^ xsw) * 8));
        #pragma unroll
        for (int mi = 0; mi < MI; ++mi)
            afr[mi] = *(const bf16x8*)(As[cur] + (wm * (BM2 / 2) + mi * 16 + l15) * 32 + ((lg ^ xsw) * 8));
        #pragma unroll
        for (int mi = 0; mi < MI; ++mi)
            #pragma unroll
            for (int nj = 0; nj < NJ; ++nj)
                acc[mi][nj] = __builtin_amdgcn_mfma_f32_16x16x32_bf16(afr[mi], bfr[nj], acc[mi][nj], 0, 0, 0);
        __syncthreads();
    }

    #pragma unroll
    for (int mi = 0; mi < MI; ++mi) {
        #pragma unroll
        for (int nj = 0; nj < NJ; ++nj) {
            int n = col0 + wn * (BN2 / 2) + nj * 16 + l15;
            if (n >= Nreal) continue;
            if (MODE == 1) {
                int which = n >= 400 ? 2 : (n >= 200 ? 1 : 0);
                int hd = n - which * 200;
                int h = hd / 20, d = hd - h * 20;
                int m0 = row0 + wm * (BM2 / 2) + mi * 16 + 4 * lg;
                int b = m0 >> 8, s0 = m0 & 255;
                size_t base = (size_t)(b * Hz + h) * 8192;
                if (which == 2) {
                    short4 o4;
                    float vb = bias2[hd];
                    #pragma unroll
                    for (int r = 0; r < 4; ++r)
                        ((short*)&o4)[r] = f2b(acc[mi][nj][r] + vb);
                    *(short4*)(vo + base + d * 256 + (s0 ^ ((d & 7) << 3))) = o4;
                } else if (which == 0) {
                    float qb = bias[hd];
                    #pragma unroll
                    for (int r = 0; r < 4; ++r)
                        qo[base + (s0 + r) * 32 + d] = f2b((acc[mi][nj][r] + qb) * SCALE2f);
                } else {
                    #pragma unroll
                    for (int r = 0; r < 4; ++r) {
                        int s = s0 + r;
                        ko[base + s * 32 + (((d >> 3) ^ ((s >> 1) & 3)) * 8) + (d & 7)] = f2b(acc[mi][nj][r]);
                    }
                }
            } else if (MODE == 4) {
                #pragma unroll
                for (int r = 0; r < 4; ++r) {
                    int m = row0 + wm * (BM2 / 2) + mi * 16 + 4 * lg + r;
                    int bb = m / Nz, j = m - bb * Nz;
                    size_t trow = (size_t)bb * Sp + j + 1;
                    ((float*)outv)[trow * ldo + n] =
                        acc[mi][nj][r] + bias[n] + res[(size_t)(j + 1) * Dz + n];
                }
            } else {
                #pragma unroll
                for (int r = 0; r < 4; ++r) {
                    int m = row0 + wm * (BM2 / 2) + mi * 16 + 4 * lg + r;
                    if (m >= M) continue;
                    float v = acc[mi][nj][r];
                    size_t off = (size_t)m * ldo + n;
                    if (MODE == 0) {
                        ((float*)outv)[off] = v + bias[n];
                    } else if (MODE == 2) {
                        ((float*)outv)[off] = v + bias[n] + res[off];
                    } else {
                        ((short*)outv)[off] = f2b(gelu_f(v + bias[n]));
                    }
                }
            }
        }
    }
}

// ---------------- MFMA attention v5: swapped QK^T + defer-max + cvt_pk + setprio --------
// 1280 blocks: (bh, q-half). LDS: Ks 16KB + Vt 16KB + Pl 18KB = 50.25KB.
#define PLD 72
__global__ __launch_bounds__(256) void attn5_k(const short* __restrict__ Qb,
                                               const short* __restrict__ Kb,
                                               const short* __restrict__ Vtb,
                                               const short* __restrict__ biasC,
                                               short* __restrict__ o) {
    const int blk = blockIdx.x;
    const int qb = blk & 1;
    const int bh = blk >> 1;
    const int b = bh / Hz, h = bh - b * Hz;
    __shared__ short Ks[8192];
    __shared__ short Vt[8192];
    __shared__ short Pl[4][32 * PLD];
    const int t = threadIdx.x;
    const int lane = t & 63, w = t >> 6;
    const int l15 = lane & 15, lg = lane >> 4;

    const short* kbh = Kb + (size_t)bh * 8192;
    const short* vbh = Vtb + (size_t)bh * 8192;
    #pragma unroll
    for (int i = 0; i < 4; ++i) {
        int j = w * 4 + i;
        gll16(kbh + (size_t)(j * 64 + lane) * 8, Ks + j * 512);
        gll16(vbh + (size_t)(j * 64 + lane) * 8, Vt + j * 512);
    }
    bf16x8 qfrag[2];
    const short* qbh = Qb + (size_t)bh * 8192;
    #pragma unroll
    for (int mi = 0; mi < 2; ++mi) {
        int qrow = qb * 128 + w * 32 + mi * 16 + l15;
        qfrag[mi] = *(const bf16x8*)(qbh + qrow * 32 + lg * 8);
    }
    const short* bpp = biasC + 4 * (size_t)(lane + 128 * w + 512 * qb + 16384 * h);
    __syncthreads();

    f32x4 O[2][2];
    float mrow[2] = {-1e30f, -1e30f};
    float lrow[2] = {0.f, 0.f};
    {
        f32x4 z = {0.f, 0.f, 0.f, 0.f};
        O[0][0] = z; O[0][1] = z; O[1][0] = z; O[1][1] = z;
    }
    const int xsw = (l15 >> 1) & 3;

    #pragma unroll 1
    for (int kc = 0; kc < 4; ++kc) {
        bf16x8 kf[4];
        #pragma unroll
        for (int nj = 0; nj < 4; ++nj)
            kf[nj] = *(const bf16x8*)(Ks + (kc * 64 + nj * 16 + l15) * 32 + ((lg ^ xsw) * 8));
        f32x4 s[2][4];
        __builtin_amdgcn_s_setprio(1);
        #pragma unroll
        for (int mi = 0; mi < 2; ++mi)
            #pragma unroll
            for (int nj = 0; nj < 4; ++nj) {
                f32x4 z = {0.f, 0.f, 0.f, 0.f};
                s[mi][nj] = __builtin_amdgcn_mfma_f32_16x16x32_bf16(kf[nj], qfrag[mi], z, 0, 0, 0);
            }
        __builtin_amdgcn_s_setprio(0);
        const short* bkc = bpp + kc * 16384;
        #pragma unroll
        for (int mi = 0; mi < 2; ++mi)
            #pragma unroll
            for (int nj = 0; nj < 4; ++nj) {
                short4 bp4 = *(const short4*)(bkc + nj * 4096 + mi * 256);
                s[mi][nj][0] += b2f(bp4.x);
                s[mi][nj][1] += b2f(bp4.y);
                s[mi][nj][2] += b2f(bp4.z);
                s[mi][nj][3] += b2f(bp4.w);
            }
        #pragma unroll
        for (int mi = 0; mi < 2; ++mi) {
            float mx = s[mi][0][0];
            #pragma unroll
            for (int nj = 0; nj < 4; ++nj)
                #pragma unroll
                for (int c = 0; c < 4; ++c) mx = fmaxf(mx, s[mi][nj][c]);
            mx = fmaxf(mx, __shfl_xor(mx, 16));
            mx = fmaxf(mx, __shfl_xor(mx, 32));
            float ssum = 0.f;
            if (__all(mx - mrow[mi] <= 8.f)) {
                float mn = mrow[mi];
                #pragma unroll
                for (int nj = 0; nj < 4; ++nj)
                    #pragma unroll
                    for (int c = 0; c < 4; ++c) {
                        float p = exp2f(s[mi][nj][c] - mn);
                        s[mi][nj][c] = p;
                        ssum += p;
                    }
                ssum += __shfl_xor(ssum, 16);
                ssum += __shfl_xor(ssum, 32);
                lrow[mi] += ssum;
            } else {
                float mn = fmaxf(mrow[mi], mx);
                float scn = exp2f(mrow[mi] - mn);
                mrow[mi] = mn;
                #pragma unroll
                for (int nj = 0; nj < 4; ++nj)
                    #pragma unroll
                    for (int c = 0; c < 4; ++c) {
                        float p = exp2f(s[mi][nj][c] - mn);
                        s[mi][nj][c] = p;
                        ssum += p;
                    }
                ssum += __shfl_xor(ssum, 16);
                ssum += __shfl_xor(ssum, 32);
                lrow[mi] = lrow[mi] * scn + ssum;
                f32x4 scd;
                #pragma unroll
                for (int r = 0; r < 4; ++r) scd[r] = __shfl(scn, 4 * lg + r);
                O[mi][0] *= scd;
                O[mi][1] *= scd;
            }
            #pragma unroll
            for (int nj = 0; nj < 4; ++nj)
                *(uint2*)(Pl[w] + (mi * 16 + l15) * PLD + nj * 16 + 4 * lg) =
                    pk4(s[mi][nj][0], s[mi][nj][1], s[mi][nj][2], s[mi][nj][3]);
        }
        #pragma unroll
        for (int kk = 0; kk < 2; ++kk) {
            bf16x8 vf[2];
            #pragma unroll
            for (int dj = 0; dj < 2; ++dj) {
                int d = dj * 16 + l15;
                int cb = (kc * 128 + kk * 64 + lg * 16) ^ ((l15 & 7) << 4);
                vf[dj] = *(const bf16x8*)((const char*)Vt + d * 512 + cb);
            }
            __builtin_amdgcn_s_setprio(1);
            #pragma unroll
            for (int mi = 0; mi < 2; ++mi) {
                bf16x8 af = *(const bf16x8*)(Pl[w] + (mi * 16 + l15) * PLD + kk * 32 + lg * 8);
                O[mi][0] = __builtin_amdgcn_mfma_f32_16x16x32_bf16(af, vf[0], O[mi][0], 0, 0, 0);
                O[mi][1] = __builtin_amdgcn_mfma_f32_16x16x32_bf16(af, vf[1], O[mi][1], 0, 0, 0);
            }
            __builtin_amdgcn_s_setprio(0);
        }
    }

    #pragma unroll
    for (int mi = 0; mi < 2; ++mi) {
        float linv = 1.f / lrow[mi];
        f32x4 invd;
        #pragma unroll
        for (int r = 0; r < 4; ++r) invd[r] = __shfl(linv, 4 * lg + r);
        #pragma unroll
        for (int dj = 0; dj < 2; ++dj) {
            int d = dj * 16 + l15;
            if (d >= HDz) continue;
            #pragma unroll
            for (int r = 0; r < 4; ++r) {
                int q = qb * 128 + w * 32 + mi * 16 + 4 * lg + r;
                if (q < Sz)
                    o[((size_t)b * Sp + q) * Kp + h * HDz + d] = f2b(O[mi][dj][r] * invd[r]);
            }
        }
    }
}

// ---------------- pool + fc_norm -> bf16 pooled ----------------
__global__ void pool_norm_k(const float* __restrict__ tok, const float* __restrict__ sc,
                            const float* __restrict__ bi, short* __restrict__ pooled) {
    int b = blockIdx.x;
    int t = threadIdx.x;
    float val = 0.f;
    if (t < Dz) {
        const float* base = tok + ((size_t)b * Sp + 1) * Dz + t;
        float s = 0.f;
        for (int si = 0; si < Nz; ++si) s += base[(size_t)si * Dz];
        val = s * (1.f / Nz);
    }
    __shared__ float red[8];
    float sum = val, sq = val * val;
    #pragma unroll
    for (int off = 32; off; off >>= 1) { sum += __shfl_xor(sum, off); sq += __shfl_xor(sq, off); }
    int wave = t >> 6, lane = t & 63;
    if (lane == 0) { red[wave] = sum; red[4 + wave] = sq; }
    __syncthreads();
    sum = red[0] + red[1] + red[2] + red[3];
    sq = red[4] + red[5] + red[6] + red[7];
    float mean = sum * (1.f / Dz);
    float var = sq * (1.f / Dz) - mean * mean;
    float rstd = rsqrtf(var + 1e-6f);
    if (t < Dz) pooled[(size_t)b * Kp + t] = f2b((val - mean) * rstd * sc[t] + bi[t]);
    else if (t < Kp) pooled[(size_t)b * Kp + t] = 0;
}

extern "C" void kernel_launch(void* const* d_in, const int* in_sizes, int n_in,
                              void* d_out, int out_size, void* d_ws, size_t ws_size,
                              hipStream_t stream) {
    const float* x        = (const float*)d_in[0];
    const float* conv_w   = (const float*)d_in[1];
    const float* conv_b   = (const float*)d_in[2];
    const float* cls_tok  = (const float*)d_in[3];
    const float* pos_emb  = (const float*)d_in[4];
    const float* ln1_s    = (const float*)d_in[5];
    const float* ln1_b    = (const float*)d_in[6];
    const float* qkv_w    = (const float*)d_in[7];
    const float* q_bias   = (const float*)d_in[8];
    const float* v_bias   = (const float*)d_in[9];
    const float* rpb      = (const float*)d_in[10];
    const float* proj_w   = (const float*)d_in[11];
    const float* proj_b   = (const float*)d_in[12];
    const float* ln2_s    = (const float*)d_in[13];
    const float* ln2_b    = (const float*)d_in[14];
    const float* fc1_w    = (const float*)d_in[15];
    const float* fc1_b    = (const float*)d_in[16];
    const float* fc2_w    = (const float*)d_in[17];
    const float* fc2_b    = (const float*)d_in[18];
    const float* fcn_s    = (const float*)d_in[19];
    const float* fcn_b    = (const float*)d_in[20];
    const float* head_w   = (const float*)d_in[21];
    const float* head_b   = (const float*)d_in[22];
    float* out = (float*)d_out;

    char* ws = (char*)d_ws;
    float* tok  = (float*)ws;  ws += (size_t)Mp * Dz * 4;        // 13.11 MB
    short* xln  = (short*)ws;  ws += (size_t)Mp * Kp * 2;        // 7.34 MB
    short* mid  = (short*)ws;  ws += (size_t)Mp * FFz * 2;       // 26.21 MB
    short* Qb   = (short*)ws;  ws += (size_t)640 * 8192 * 2;     // 10.49 MB
    short* Kb   = (short*)ws;  ws += (size_t)640 * 8192 * 2;
    short* Vtb  = (short*)ws;  ws += (size_t)640 * 8192 * 2;
    short* wq = (short*)ws;    ws += (size_t)Lz * 640 * Kp * 2;
    short* wp = (short*)ws;    ws += (size_t)Lz * 256 * Kp * 2;
    short* w1 = (short*)ws;    ws += (size_t)Lz * 896 * Kp * 2;
    short* w2 = (short*)ws;    ws += (size_t)Lz * 256 * FFz * 2;
    short* wh = (short*)ws;    ws += (size_t)1024 * Kp * 2;
    short* biasC = (short*)ws; ws += (size_t)Lz * BIASL * 2;     // 15.7 MB
    short* xb   = (short*)ws;  ws += (size_t)PEM * 64 * 2;       // 1.97 MB
    short* wpe  = (short*)ws;  ws += (size_t)256 * 64 * 2;
    short* pooledb = (short*)ws; ws += (size_t)128 * Kp * 2;     // head A (rows 64..127 pad)

    hipMemsetAsync(xln, 0, (size_t)Mp * Kp * 2, stream);
    hipMemsetAsync(Qb, 0, (size_t)640 * 8192 * 2 * 3, stream);
    hipMemsetAsync(pooledb, 0, (size_t)128 * Kp * 2, stream);

    {
        int n;
        n = Lz * 640 * Kp;  cvt_pad_k<<<(n + 255) / 256, 256, 0, stream>>>(qkv_w, wq, 600, 200, 640, Kp, n);
        n = Lz * 256 * Kp;  cvt_pad_k<<<(n + 255) / 256, 256, 0, stream>>>(proj_w, wp, 200, 200, 256, Kp, n);
        n = Lz * 896 * Kp;  cvt_pad_k<<<(n + 255) / 256, 256, 0, stream>>>(fc1_w, w1, 800, 200, 896, Kp, n);
        n = Lz * 256 * FFz; cvt_pad_k<<<(n + 255) / 256, 256, 0, stream>>>(fc2_w, w2, 200, 800, 256, FFz, n);
        n = 1024 * Kp;      cvt_pad_k<<<(n + 255) / 256, 256, 0, stream>>>(head_w, wh, 1000, 200, 1024, Kp, n);
        n = 256 * 64;       cvt_pad_k<<<(n + 255) / 256, 256, 0, stream>>>(conv_w, wpe, 200, 50, 256, 64, n);
    }
    bias_pre4_k<<<dim3(640, Lz), 256, 0, stream>>>(rpb, biasC);

    // patch embed as MFMA GEMM
    xcvt_k<<<(PEM * 64) / 256, 256, 0, stream>>>(x, xb);
    gemm4_k<4, 64, 128><<<4 * (PEM / 128), 256, 0, stream>>>(
        xb, wpe, conv_b, nullptr, pos_emb, tok,
        nullptr, nullptr, nullptr, PEM, Dz, 64, 64, Dz, 4, PEM / 128);
    cls_k<<<Bz, 256, 0, stream>>>(cls_tok, pos_emb, tok);

    dim3 blk(256);
    for (int l = 0; l < Lz; ++l) {
        ln_k<<<Mp / 4, blk, 0, stream>>>(tok, xln, ln1_s + l * Dz, ln1_b + l * Dz);
        gemm4_k<1, 128, 128><<<5 * (Mp / 128), blk, 0, stream>>>(
            xln, wq + (size_t)l * 640 * Kp, q_bias + l * Dz, v_bias + l * Dz,
            nullptr, nullptr, Qb, Kb, Vtb, Mp, 600, Kp, Kp, 0, 5, Mp / 128);
        attn5_k<<<1280, blk, 0, stream>>>(Qb, Kb, Vtb, biasC + (size_t)l * BIASL, xln);
        gemm4_k<2, 64, 64><<<4 * (Mp / 64), blk, 0, stream>>>(
            xln, wp + (size_t)l * 256 * Kp, proj_b + l * Dz, nullptr,
            tok, tok, nullptr, nullptr, nullptr, Mp, Dz, Kp, Kp, Dz, 4, Mp / 64);
        ln_k<<<Mp / 4, blk, 0, stream>>>(tok, xln, ln2_s + l * Dz, ln2_b + l * Dz);
        gemm4_k<3, 128, 128><<<7 * (Mp / 128), blk, 0, stream>>>(
            xln, w1 + (size_t)l * 896 * Kp, fc1_b + l * FFz, nullptr,
            nullptr, mid, nullptr, nullptr, nullptr, Mp, FFz, Kp, Kp, FFz, 7, Mp / 128);
        gemm4_k<2, 64, 64><<<4 * (Mp / 64), blk, 0, stream>>>(
            mid, w2 + (size_t)l * 256 * FFz, fc2_b + l * Dz, nullptr,
            tok, tok, nullptr, nullptr, nullptr, Mp, Dz, FFz, FFz, Dz, 4, Mp / 64);
    }

    pool_norm_k<<<Bz, blk, 0, stream>>>(tok, fcn_s, fcn_b, pooledb);
    gemm4_k<0, 128, 128><<<8, blk, 0, stream>>>(
        pooledb, wh, head_b, nullptr, nullptr, out,
        nullptr, nullptr, nullptr, Bz, NCz, Kp, Kp, NCz, 8, 1);
}